// Round 1
// baseline (550.349 us; speedup 1.0000x reference)
//
#include <hip/hip_runtime.h>
#include <hip/hip_bf16.h>
#include <math.h>

#define DI __device__ __forceinline__

typedef __bf16 bf16_t;
typedef bf16_t bf16x8 __attribute__((ext_vector_type(8)));
typedef bf16_t bf16x4 __attribute__((ext_vector_type(4)));
typedef float f32x4 __attribute__((ext_vector_type(4)));

constexpr int S_ = 1024, B_ = 2, E_ = 1024, H_ = 16, HD_ = 64;
constexpr int T_ = S_ * B_;      // 2048 tokens
constexpr int DFF_ = 4096, NE_ = 8;

DI f32x4 mfma16(bf16x8 a, bf16x8 b, f32x4 c) {
  return __builtin_amdgcn_mfma_f32_16x16x32_bf16(a, b, c, 0, 0, 0);
}

// split fp32 into hi/lo bf16 (v ~= hi + lo, residual ~2^-18 relative)
DI void split2(float v, bf16_t& h, bf16_t& l) {
  h = (bf16_t)v;
  l = (bf16_t)(v - (float)h);
}

// ---------------------------------------------------------------------------
// Generic 128x128-tile MFMA GEMM.  C[m,n] = sum_k A[m,k]*B[n,k]  (B given
// row-major [N][K], i.e. B^T form).  MODE selects A source + epilogue.
// MODE 0: QKV    A=x fp32 (split),   epi: +bias, scale Q, scatter hi/lo QKV
// MODE 1: OUTPROJ A=attn hi/lo bf16 (split), epi: +bias +x residual -> f32
// MODE 2: MOE1   A=ln1 bf16 gathered via perm (single), epi: +b1, gelu -> bf16
// MODE 3: MOE2   A=hbuf bf16 (single), epi: +b2 +ln1 residual, scatter -> f32
// ---------------------------------------------------------------------------
template <int MODE>
__launch_bounds__(256)
__global__ void gemm_kernel(const float* Af32, const bf16_t* Abh, const bf16_t* Abl,
                            const float* Bw, const float* bias, const float* res,
                            float* Cf32, bf16_t* Cbf,
                            bf16_t* Qh, bf16_t* Ql, bf16_t* Kh2, bf16_t* Kl2,
                            bf16_t* Vh2, bf16_t* Vl2,
                            const int* offs, const int* perm, int Kdim) {
  constexpr bool SPLIT = (MODE <= 1);
  constexpr int BK = SPLIT ? 32 : 64;
  constexpr int LDST = BK + 8;  // padded stride: 80B / 144B rows -> 16B aligned
  extern __shared__ char smem[];
  bf16_t* Ah = (bf16_t*)smem;
  bf16_t* Al = Ah + (SPLIT ? 128 * LDST : 0);
  bf16_t* Bh = Ah + (SPLIT ? 2 : 1) * 128 * LDST;
  bf16_t* Bl = Bh + (SPLIT ? 128 * LDST : 0);

  const int tid = threadIdx.x, lane = tid & 63, wv = tid >> 6;
  const int n0 = blockIdx.x * 128, m0 = blockIdx.y * 128;
  const int e = blockIdx.z;

  int pBase = 0, pEnd = 1 << 30, mBase = m0;
  if constexpr (MODE >= 2) {
    pBase = offs[e];
    pEnd = offs[e + 1];
    mBase = pBase + m0;
    if (mBase >= pEnd) return;  // uniform early exit, before any barrier
  }
  const float* Bp = Bw;
  if constexpr (MODE == 2) Bp += (size_t)e * DFF_ * E_;
  if constexpr (MODE == 3) Bp += (size_t)e * E_ * DFF_;

  f32x4 acc[4][4];
#pragma unroll
  for (int i = 0; i < 4; i++)
#pragma unroll
    for (int j = 0; j < 4; j++) acc[i][j] = (f32x4){0.f, 0.f, 0.f, 0.f};

  const int wm = (wv >> 1) * 64, wn = (wv & 1) * 64;
  const int lr = lane & 15, lk = (lane >> 4) * 8;

  const int nK = Kdim / BK;
  for (int kt = 0; kt < nK; ++kt) {
    const int k0 = kt * BK;
    __syncthreads();
    // ---- stage A tile [128][BK] ----
    if constexpr (MODE == 0) {
#pragma unroll
      for (int i = 0; i < 4; i++) {
        int f = tid + i * 256, row = f >> 3, col = (f & 7) * 4;
        f32x4 v = *(const f32x4*)&Af32[(size_t)(m0 + row) * Kdim + k0 + col];
        bf16x4 hv, lv;
#pragma unroll
        for (int j = 0; j < 4; j++) { bf16_t hh, ll; split2(v[j], hh, ll); hv[j] = hh; lv[j] = ll; }
        *(bf16x4*)&Ah[row * LDST + col] = hv;
        *(bf16x4*)&Al[row * LDST + col] = lv;
      }
    } else if constexpr (MODE == 1) {
#pragma unroll
      for (int i = 0; i < 2; i++) {
        int f = tid + i * 256, row = f >> 2, col = (f & 3) * 8;
        *(bf16x8*)&Ah[row * LDST + col] = *(const bf16x8*)&Abh[(size_t)(m0 + row) * Kdim + k0 + col];
        *(bf16x8*)&Al[row * LDST + col] = *(const bf16x8*)&Abl[(size_t)(m0 + row) * Kdim + k0 + col];
      }
    } else {
#pragma unroll
      for (int i = 0; i < 4; i++) {
        int f = tid + i * 256, row = f >> 3, col = (f & 7) * 8;
        int p = mBase + row;
        int src;
        if constexpr (MODE == 2) src = (p < pEnd) ? perm[p] : 0;
        else                     src = (p < pEnd) ? p : pBase;
        *(bf16x8*)&Ah[row * LDST + col] = *(const bf16x8*)&Abh[(size_t)src * Kdim + k0 + col];
      }
    }
    // ---- stage B tile [128][BK] (always fp32 weights) ----
    {
      constexpr int ITER = (BK == 32) ? 4 : 8;
#pragma unroll
      for (int i = 0; i < ITER; i++) {
        int f = tid + i * 256;
        int row = (BK == 32) ? (f >> 3) : (f >> 4);
        int col = (BK == 32) ? ((f & 7) * 4) : ((f & 15) * 4);
        f32x4 v = *(const f32x4*)&Bp[(size_t)(n0 + row) * Kdim + k0 + col];
        if constexpr (SPLIT) {
          bf16x4 hv, lv;
#pragma unroll
          for (int j = 0; j < 4; j++) { bf16_t hh, ll; split2(v[j], hh, ll); hv[j] = hh; lv[j] = ll; }
          *(bf16x4*)&Bh[row * LDST + col] = hv;
          *(bf16x4*)&Bl[row * LDST + col] = lv;
        } else {
          bf16x4 hv;
#pragma unroll
          for (int j = 0; j < 4; j++) hv[j] = (bf16_t)v[j];
          *(bf16x4*)&Bh[row * LDST + col] = hv;
        }
      }
    }
    __syncthreads();
    // ---- MFMA ----
#pragma unroll
    for (int kk = 0; kk < BK / 32; ++kk) {
      bf16x8 afh[4], afl[4];
#pragma unroll
      for (int fm = 0; fm < 4; fm++) {
        afh[fm] = *(const bf16x8*)&Ah[(wm + fm * 16 + lr) * LDST + kk * 32 + lk];
        if constexpr (SPLIT)
          afl[fm] = *(const bf16x8*)&Al[(wm + fm * 16 + lr) * LDST + kk * 32 + lk];
      }
#pragma unroll
      for (int fn = 0; fn < 4; fn++) {
        bf16x8 bfh = *(const bf16x8*)&Bh[(wn + fn * 16 + lr) * LDST + kk * 32 + lk];
        bf16x8 bfl;
        if constexpr (SPLIT)
          bfl = *(const bf16x8*)&Bl[(wn + fn * 16 + lr) * LDST + kk * 32 + lk];
#pragma unroll
        for (int fm = 0; fm < 4; fm++) {
          acc[fm][fn] = mfma16(afh[fm], bfh, acc[fm][fn]);
          if constexpr (SPLIT) {
            acc[fm][fn] = mfma16(afh[fm], bfl, acc[fm][fn]);
            acc[fm][fn] = mfma16(afl[fm], bfh, acc[fm][fn]);
          }
        }
      }
    }
  }
  // ---- epilogue.  C/D layout: col = lane&15, row = (lane>>4)*4 + reg ----
  const int lr4 = (lane >> 4) * 4;
#pragma unroll
  for (int fm = 0; fm < 4; fm++) {
#pragma unroll
    for (int fn = 0; fn < 4; fn++) {
#pragma unroll
      for (int r = 0; r < 4; r++) {
        float v = acc[fm][fn][r];
        int row = wm + fm * 16 + lr4 + r;
        int col = wn + fn * 16 + lr;
        if constexpr (MODE == 0) {
          int gm = m0 + row, gn = n0 + col;
          v += bias[gn];
          int sec = gn >> 10, ee = gn & 1023, hh = ee >> 6, dd = ee & 63;
          if (sec == 0) v *= 0.125f;  // 1/sqrt(64), applied after bias like ref
          int ss = gm >> 1, bb = gm & 1, bhp = bb * 16 + hh;
          size_t di = ((size_t)bhp * 1024 + ss) * 64 + dd;
          bf16_t oh, ol; split2(v, oh, ol);
          bf16_t* dh = (sec == 0) ? Qh : (sec == 1) ? Kh2 : Vh2;
          bf16_t* dl = (sec == 0) ? Ql : (sec == 1) ? Kl2 : Vl2;
          dh[di] = oh; dl[di] = ol;
        } else if constexpr (MODE == 1) {
          int gm = m0 + row, gn = n0 + col;
          v += bias[gn] + res[(size_t)gm * E_ + gn];
          Cf32[(size_t)gm * E_ + gn] = v;
        } else if constexpr (MODE == 2) {
          int p = mBase + row;
          if (p < pEnd) {
            int gn = n0 + col;
            v += bias[e * DFF_ + gn];
            v = 0.5f * v * (1.0f + erff(v * 0.70710678118654752440f));  // exact gelu
            Cbf[(size_t)p * DFF_ + gn] = (bf16_t)v;
          }
        } else {
          int p = mBase + row;
          if (p < pEnd) {
            int t = perm[p];
            int gn = n0 + col;
            v += bias[e * E_ + gn] + res[(size_t)t * E_ + gn];
            Cf32[(size_t)t * E_ + gn] = v;
          }
        }
      }
    }
  }
}

// ---------------------------------------------------------------------------
// V transpose: [bh][s][d] -> [bh][d][s] (hi and lo), LDS-tiled, coalesced.
// ---------------------------------------------------------------------------
__launch_bounds__(256)
__global__ void vtrans_kernel(const bf16_t* vh, const bf16_t* vl,
                              bf16_t* vth, bf16_t* vtl) {
  const int bh = blockIdx.y, s0 = blockIdx.x * 64;
  const int tid = threadIdx.x;
  __shared__ bf16_t th[64][72];
  __shared__ bf16_t tl[64][72];
#pragma unroll
  for (int i = 0; i < 2; i++) {
    int f = tid + i * 256, r = f >> 3, c = (f & 7) * 8;
    size_t g = ((size_t)bh * 1024 + s0 + r) * 64 + c;
    *(bf16x8*)&th[r][c] = *(const bf16x8*)&vh[g];
    *(bf16x8*)&tl[r][c] = *(const bf16x8*)&vl[g];
  }
  __syncthreads();
#pragma unroll
  for (int i = 0; i < 2; i++) {
    int f = tid + i * 256, d = f >> 3, c2 = (f & 7) * 8;
    bf16x8 oh, ol;
#pragma unroll
    for (int j = 0; j < 8; j++) { oh[j] = th[c2 + j][d]; ol[j] = tl[c2 + j][d]; }
    size_t g = ((size_t)bh * 64 + d) * 1024 + s0 + c2;
    *(bf16x8*)&vth[g] = oh;
    *(bf16x8*)&vtl[g] = ol;
  }
}

// ---------------------------------------------------------------------------
// Flash attention, split-bf16.  Block = (q-tile of 64 rows) x (one bh).
// 4 waves; wave owns 16 q rows.  KV tiles of 64.  Online softmax in fp32.
// ---------------------------------------------------------------------------
__launch_bounds__(256)
__global__ void attn_kernel(const bf16_t* gqh, const bf16_t* gql,
                            const bf16_t* gkh, const bf16_t* gkl,
                            const bf16_t* gvth, const bf16_t* gvtl,
                            bf16_t* aoh, bf16_t* aol) {
  const int bh = blockIdx.y, q0 = blockIdx.x * 64;
  const int tid = threadIdx.x, lane = tid & 63, wv = tid >> 6;
  const int lr = lane & 15, lk = (lane >> 4) * 8, lr4 = (lane >> 4) * 4;
  extern __shared__ char smem[];
  bf16_t* Kh = (bf16_t*)smem;       // [64][72]
  bf16_t* Kl = Kh + 64 * 72;
  bf16_t* Vh = Kl + 64 * 72;        // transposed [d][t]
  bf16_t* Vl = Vh + 64 * 72;
  bf16_t* Ph = Vl + 64 * 72;        // [64][72], wave w owns rows [16w,16w+16)
  bf16_t* Pl = Ph + 64 * 72;

  // Q fragments (held in registers all kernel).  A row = lane&15.
  const size_t qbase = ((size_t)bh * 1024 + q0 + wv * 16 + lr) * 64;
  bf16x8 qfh[2], qfl[2];
  qfh[0] = *(const bf16x8*)&gqh[qbase + lk];
  qfh[1] = *(const bf16x8*)&gqh[qbase + 32 + lk];
  qfl[0] = *(const bf16x8*)&gql[qbase + lk];
  qfl[1] = *(const bf16x8*)&gql[qbase + 32 + lk];

  f32x4 oacc[4];
#pragma unroll
  for (int i = 0; i < 4; i++) oacc[i] = (f32x4){0.f, 0.f, 0.f, 0.f};
  float m_r[4], l_r[4];
#pragma unroll
  for (int r = 0; r < 4; r++) { m_r[r] = -INFINITY; l_r[r] = 0.f; }

  for (int t0 = 0; t0 < S_; t0 += 64) {
    __syncthreads();
    // stage K [t][d] and V^T [d][t] tiles
#pragma unroll
    for (int i = 0; i < 2; i++) {
      int f = tid + i * 256, r = f >> 3, c = (f & 7) * 8;
      size_t gk = ((size_t)bh * 1024 + t0 + r) * 64 + c;
      *(bf16x8*)&Kh[r * 72 + c] = *(const bf16x8*)&gkh[gk];
      *(bf16x8*)&Kl[r * 72 + c] = *(const bf16x8*)&gkl[gk];
      size_t gv = ((size_t)bh * 64 + r) * 1024 + t0 + c;
      *(bf16x8*)&Vh[r * 72 + c] = *(const bf16x8*)&gvth[gv];
      *(bf16x8*)&Vl[r * 72 + c] = *(const bf16x8*)&gvtl[gv];
    }
    __syncthreads();
    // QK^T (split, 3 terms)
    f32x4 sacc[4];
#pragma unroll
    for (int i = 0; i < 4; i++) sacc[i] = (f32x4){0.f, 0.f, 0.f, 0.f};
#pragma unroll
    for (int kk = 0; kk < 2; ++kk) {
#pragma unroll
      for (int fn = 0; fn < 4; ++fn) {
        bf16x8 kbh = *(const bf16x8*)&Kh[(fn * 16 + lr) * 72 + kk * 32 + lk];
        bf16x8 kbl = *(const bf16x8*)&Kl[(fn * 16 + lr) * 72 + kk * 32 + lk];
        sacc[fn] = mfma16(qfh[kk], kbh, sacc[fn]);
        sacc[fn] = mfma16(qfh[kk], kbl, sacc[fn]);
        sacc[fn] = mfma16(qfl[kk], kbh, sacc[fn]);
      }
    }
    // online softmax, rows = (lane>>4)*4 + r, cols spread over lane&15 x fn
#pragma unroll
    for (int r = 0; r < 4; r++) {
      float mx = fmaxf(fmaxf(sacc[0][r], sacc[1][r]), fmaxf(sacc[2][r], sacc[3][r]));
#pragma unroll
      for (int off = 1; off < 16; off <<= 1) mx = fmaxf(mx, __shfl_xor(mx, off));
      float mn = fmaxf(m_r[r], mx);
      float al = expf(m_r[r] - mn);   // first tile: exp(-inf)=0
      l_r[r] *= al;
#pragma unroll
      for (int fd = 0; fd < 4; fd++) oacc[fd][r] *= al;
      float ps = 0.f;
      int pr = wv * 16 + lr4 + r;
#pragma unroll
      for (int fn = 0; fn < 4; fn++) {
        float p = expf(sacc[fn][r] - mn);
        ps += p;
        bf16_t ph, pl; split2(p, ph, pl);
        Ph[pr * 72 + fn * 16 + lr] = ph;
        Pl[pr * 72 + fn * 16 + lr] = pl;
      }
#pragma unroll
      for (int off = 1; off < 16; off <<= 1) ps += __shfl_xor(ps, off);
      l_r[r] += ps;
      m_r[r] = mn;
    }
    __syncthreads();
    // PV (split, 3 terms).  A=P (k=t), B=V^T rows d.
#pragma unroll
    for (int kk = 0; kk < 2; kk++) {
      bf16x8 pah = *(const bf16x8*)&Ph[(wv * 16 + lr) * 72 + kk * 32 + lk];
      bf16x8 pal = *(const bf16x8*)&Pl[(wv * 16 + lr) * 72 + kk * 32 + lk];
#pragma unroll
      for (int fd = 0; fd < 4; fd++) {
        bf16x8 vbh = *(const bf16x8*)&Vh[(fd * 16 + lr) * 72 + kk * 32 + lk];
        bf16x8 vbl = *(const bf16x8*)&Vl[(fd * 16 + lr) * 72 + kk * 32 + lk];
        oacc[fd] = mfma16(pah, vbh, oacc[fd]);
        oacc[fd] = mfma16(pah, vbl, oacc[fd]);
        oacc[fd] = mfma16(pal, vbh, oacc[fd]);
      }
    }
  }
  // epilogue: O/l -> attn_out [token][E] hi/lo
  const int b = bh >> 4, h = bh & 15;
#pragma unroll
  for (int fd = 0; fd < 4; fd++) {
#pragma unroll
    for (int r = 0; r < 4; r++) {
      float v = oacc[fd][r] / l_r[r];
      int s = q0 + wv * 16 + lr4 + r;
      int d = fd * 16 + lr;
      size_t idx = ((size_t)(s * 2 + b)) * 1024 + h * 64 + d;
      bf16_t oh, ol; split2(v, oh, ol);
      aoh[idx] = oh;
      aol[idx] = ol;
    }
  }
}

// ---------------------------------------------------------------------------
// Row LayerNorm over E=1024.  WHICH=1: write f32 + bf16.  WHICH=2: f32 only.
// ---------------------------------------------------------------------------
template <int WHICH>
__launch_bounds__(256)
__global__ void ln_kernel(const float* in, const float* g, const float* bt,
                          float* outf, bf16_t* outb) {
  const int row = blockIdx.x, tid = threadIdx.x;
  f32x4 v = *(const f32x4*)&in[(size_t)row * 1024 + tid * 4];
  float s = v[0] + v[1] + v[2] + v[3];
  float q = v[0] * v[0] + v[1] * v[1] + v[2] * v[2] + v[3] * v[3];
#pragma unroll
  for (int off = 1; off < 64; off <<= 1) { s += __shfl_xor(s, off); q += __shfl_xor(q, off); }
  __shared__ float ss[4], qq[4];
  int wv = tid >> 6;
  if ((tid & 63) == 0) { ss[wv] = s; qq[wv] = q; }
  __syncthreads();
  s = ss[0] + ss[1] + ss[2] + ss[3];
  q = qq[0] + qq[1] + qq[2] + qq[3];
  float mu = s * (1.f / 1024.f);
  float var = q * (1.f / 1024.f) - mu * mu;
  float rs = rsqrtf(var + 1e-5f);
  f32x4 gg = *(const f32x4*)&g[tid * 4];
  f32x4 bb = *(const f32x4*)&bt[tid * 4];
  f32x4 o;
#pragma unroll
  for (int j = 0; j < 4; j++) o[j] = (v[j] - mu) * rs * gg[j] + bb[j];
  *(f32x4*)&outf[(size_t)row * 1024 + tid * 4] = o;
  if constexpr (WHICH == 1) {
    bf16x4 ob;
#pragma unroll
    for (int j = 0; j < 4; j++) ob[j] = (bf16_t)o[j];
    *(bf16x4*)&outb[(size_t)row * 1024 + tid * 4] = ob;
  }
}

// ---------------------------------------------------------------------------
// Gate: logits (fp32 dot), argmax (first max), per-expert counts.
// One wave per token.
// ---------------------------------------------------------------------------
__launch_bounds__(256)
__global__ void gate_kernel(const float* ln1f, const float* gw, const float* gb,
                            int* eid, int* cnt) {
  const int t = blockIdx.x * 4 + (threadIdx.x >> 6);
  const int lane = threadIdx.x & 63;
  float a[8] = {0, 0, 0, 0, 0, 0, 0, 0};
  for (int k0 = lane * 4; k0 < 1024; k0 += 256) {
    f32x4 xv = *(const f32x4*)&ln1f[(size_t)t * 1024 + k0];
#pragma unroll
    for (int ee = 0; ee < 8; ee++) {
      f32x4 wv4 = *(const f32x4*)&gw[ee * 1024 + k0];
      a[ee] += xv[0] * wv4[0] + xv[1] * wv4[1] + xv[2] * wv4[2] + xv[3] * wv4[3];
    }
  }
#pragma unroll
  for (int ee = 0; ee < 8; ee++)
#pragma unroll
    for (int off = 1; off < 64; off <<= 1) a[ee] += __shfl_xor(a[ee], off);
  if (lane == 0) {
    float best = a[0] + gb[0];
    int be = 0;
#pragma unroll
    for (int ee = 1; ee < 8; ee++) {
      float vv = a[ee] + gb[ee];
      if (vv > best) { best = vv; be = ee; }  // strict > : first-max, matches argmax
    }
    eid[t] = be;
    atomicAdd(&cnt[be], 1);
  }
}

__global__ void zero_kernel(int* cnt) {
  if (threadIdx.x < 8) cnt[threadIdx.x] = 0;
}

__global__ void scan_kernel(const int* cnt, int* offs, int* cur) {
  if (threadIdx.x == 0) {
    int o = 0;
    for (int e = 0; e < 8; e++) { offs[e] = o; o += cnt[e]; cur[e] = 0; }
    offs[8] = o;
  }
}

__global__ void scatter_kernel(const int* eid, const int* offs, int* cur, int* perm) {
  int t = blockIdx.x * 256 + threadIdx.x;
  int ee = eid[t];
  int pos = atomicAdd(&cur[ee], 1);
  perm[offs[ee] + pos] = t;
}

// ---------------------------------------------------------------------------
extern "C" void kernel_launch(void* const* d_in, const int* in_sizes, int n_in,
                              void* d_out, int out_size, void* d_ws, size_t ws_size,
                              hipStream_t stream) {
  const float* x    = (const float*)d_in[0];
  const float* ipw  = (const float*)d_in[1];
  const float* ipb  = (const float*)d_in[2];
  const float* opw  = (const float*)d_in[3];
  const float* opb  = (const float*)d_in[4];
  const float* ln1g = (const float*)d_in[5];
  const float* ln1b = (const float*)d_in[6];
  const float* ln2g = (const float*)d_in[7];
  const float* ln2b = (const float*)d_in[8];
  const float* gw   = (const float*)d_in[9];
  const float* gb   = (const float*)d_in[10];
  const float* w1   = (const float*)d_in[11];
  const float* b1   = (const float*)d_in[12];
  const float* w2   = (const float*)d_in[13];
  const float* b2   = (const float*)d_in[14];
  float* out = (float*)d_out;

  char* w = (char*)d_ws;
  auto alloc = [&](size_t n) { char* p = w; w += (n + 255) & ~(size_t)255; return p; };
  const size_t NBH = (size_t)32 * 1024 * 64;  // per Q/K/V buffer elems (2M)

  bf16_t* qh  = (bf16_t*)alloc(NBH * 2);
  bf16_t* ql  = (bf16_t*)alloc(NBH * 2);
  bf16_t* kh  = (bf16_t*)alloc(NBH * 2);
  bf16_t* kl  = (bf16_t*)alloc(NBH * 2);
  bf16_t* vh  = (bf16_t*)alloc(NBH * 2);
  bf16_t* vl  = (bf16_t*)alloc(NBH * 2);
  bf16_t* vth = (bf16_t*)alloc(NBH * 2);
  bf16_t* vtl = (bf16_t*)alloc(NBH * 2);
  bf16_t* aoh = (bf16_t*)alloc((size_t)T_ * E_ * 2);
  bf16_t* aol = (bf16_t*)alloc((size_t)T_ * E_ * 2);
  float*  pre1 = (float*)alloc((size_t)T_ * E_ * 4);
  bf16_t* l1b  = (bf16_t*)alloc((size_t)T_ * E_ * 2);
  float*  l1f  = (float*)alloc((size_t)T_ * E_ * 4);
  bf16_t* hbuf = (bf16_t*)alloc((size_t)T_ * DFF_ * 2);
  float*  pre2 = (float*)alloc((size_t)T_ * E_ * 4);
  int* eid  = (int*)alloc(T_ * 4);
  int* cnt  = (int*)alloc(16 * 4);
  int* offs = (int*)alloc(16 * 4);
  int* cur  = (int*)alloc(16 * 4);
  int* perm = (int*)alloc(T_ * 4);

  const dim3 blk(256);
  const int smemSplit  = 4 * 128 * 40 * 2;  // 40960
  const int smemSingle = 2 * 128 * 72 * 2;  // 36864
  const int smemAttn   = 6 * 64 * 72 * 2;   // 55296

  zero_kernel<<<1, 64, 0, stream>>>(cnt);

  // 1) QKV projection (split) -> Q/K/V hi/lo in [bh][s][d]
  gemm_kernel<0><<<dim3(24, 16, 1), blk, smemSplit, stream>>>(
      x, nullptr, nullptr, ipw, ipb, nullptr, nullptr, nullptr,
      qh, ql, kh, kl, vh, vl, nullptr, nullptr, 1024);

  // 2) V transpose -> [bh][d][s]
  vtrans_kernel<<<dim3(16, 32), blk, 0, stream>>>(vh, vl, vth, vtl);

  // 3) flash attention -> attn_out hi/lo [token][E]
  attn_kernel<<<dim3(16, 32), blk, smemAttn, stream>>>(qh, ql, kh, kl, vth, vtl, aoh, aol);

  // 4) out_proj + bias + residual -> pre1
  gemm_kernel<1><<<dim3(8, 16, 1), blk, smemSplit, stream>>>(
      nullptr, aoh, aol, opw, opb, x, pre1, nullptr,
      nullptr, nullptr, nullptr, nullptr, nullptr, nullptr, nullptr, nullptr, 1024);

  // 5) LN1 -> l1f (f32) + l1b (bf16)
  ln_kernel<1><<<dim3(T_), blk, 0, stream>>>(pre1, ln1g, ln1b, l1f, l1b);

  // 6) gate + routing
  gate_kernel<<<dim3(T_ / 4), blk, 0, stream>>>(l1f, gw, gb, eid, cnt);
  scan_kernel<<<1, 64, 0, stream>>>(cnt, offs, cur);
  scatter_kernel<<<dim3(T_ / 256), blk, 0, stream>>>(eid, offs, cur, perm);

  // 7) expert FFN up: h = gelu(t @ w1^T + b1) -> hbuf (bf16, slot-major)
  gemm_kernel<2><<<dim3(32, 16, 8), blk, smemSingle, stream>>>(
      nullptr, l1b, nullptr, w1, b1, nullptr, nullptr, hbuf,
      nullptr, nullptr, nullptr, nullptr, nullptr, nullptr, offs, perm, 1024);

  // 8) expert FFN down + residual -> pre2 (scattered to token rows)
  gemm_kernel<3><<<dim3(8, 16, 8), blk, smemSingle, stream>>>(
      nullptr, hbuf, nullptr, w2, b2, l1f, pre2, nullptr,
      nullptr, nullptr, nullptr, nullptr, nullptr, nullptr, offs, perm, 4096);

  // 9) LN2 -> d_out
  ln_kernel<2><<<dim3(T_), blk, 0, stream>>>(pre2, ln2g, ln2b, out, nullptr);

  (void)in_sizes; (void)n_in; (void)out_size; (void)ws_size;
}

// Round 2
// 447.365 us; speedup vs baseline: 1.2302x; 1.2302x over previous
//
#include <hip/hip_runtime.h>
#include <hip/hip_bf16.h>
#include <math.h>

#define DI __device__ __forceinline__

typedef __bf16 bf16_t;
typedef bf16_t bf16x8 __attribute__((ext_vector_type(8)));
typedef bf16_t bf16x4 __attribute__((ext_vector_type(4)));
typedef float f32x4 __attribute__((ext_vector_type(4)));

constexpr int S_ = 1024, B_ = 2, E_ = 1024, H_ = 16, HD_ = 64;
constexpr int T_ = S_ * B_;      // 2048 tokens
constexpr int DFF_ = 4096, NE_ = 8;
constexpr int SLOTS_ = 3072;     // padded slot capacity (2048 + 8*127 -> 24*128)
constexpr int SPLITK_ = 4;       // K-split for MoE down-proj

DI f32x4 mfma16(bf16x8 a, bf16x8 b, f32x4 c) {
  return __builtin_amdgcn_mfma_f32_16x16x32_bf16(a, b, c, 0, 0, 0);
}

// split fp32 into hi/lo bf16 (v ~= hi + lo, residual ~2^-18 relative)
DI void split2(float v, bf16_t& h, bf16_t& l) {
  h = (bf16_t)v;
  l = (bf16_t)(v - (float)h);
}

// ---------------------------------------------------------------------------
// Generic 128x128-tile MFMA GEMM.  C[m,n] = sum_k A[m,k]*B[n,k]  (B given
// row-major [N][K], i.e. B^T form).  MODE selects A source + epilogue.
// MODE 0: QKV     A=x fp32 (split),  epi: +bias, scale Q, scatter hi/lo QKV
// MODE 1: OUTPROJ A=attn hi/lo bf16 (split), epi: +bias +x residual -> f32
// MODE 2: MOE1    A=ln1 bf16 gathered via padded perm, epi: +b1, gelu -> bf16
//                 grid (DFF/128, 24); slot blocks are 128-aligned per expert
// MODE 3: MOE2    A=hbuf bf16 slot-major, split-K over blockIdx.z,
//                 epi: raw fp32 partial write [kz][slot][E] (reduce in LN2)
// ---------------------------------------------------------------------------
template <int MODE>
__launch_bounds__(256)
__global__ void gemm_kernel(const float* Af32, const bf16_t* Abh, const bf16_t* Abl,
                            const float* Bw, const float* bias, const float* res,
                            float* Cf32, bf16_t* Cbf,
                            bf16_t* Qh, bf16_t* Ql, bf16_t* Kh2, bf16_t* Kl2,
                            bf16_t* Vh2, bf16_t* Vl2,
                            const int* offs_pad, const int* perm, int Kdim) {
  constexpr bool SPLIT = (MODE <= 1);
  constexpr int BK = SPLIT ? 32 : 64;
  constexpr int LDST = BK + 8;  // padded stride: 80B / 144B rows -> 16B aligned
  extern __shared__ char smem[];
  bf16_t* Ah = (bf16_t*)smem;
  bf16_t* Al = Ah + (SPLIT ? 128 * LDST : 0);
  bf16_t* Bh = Ah + (SPLIT ? 2 : 1) * 128 * LDST;
  bf16_t* Bl = Bh + (SPLIT ? 128 * LDST : 0);

  const int tid = threadIdx.x, lane = tid & 63, wv = tid >> 6;
  const int n0 = blockIdx.x * 128, m0 = blockIdx.y * 128;

  int e = 0;
  if constexpr (MODE >= 2) {
    if (m0 >= offs_pad[8]) return;  // uniform early exit, before any barrier
#pragma unroll
    for (int i = 1; i < 8; i++) e += (m0 >= offs_pad[i]);
  }
  const int kz = (MODE == 3) ? blockIdx.z : 0;

  // A/B base pointers and row strides
  const bf16_t* Abase = Abh;
  const float* Bp = Bw;
  size_t lda = (size_t)Kdim, ldb = (size_t)Kdim;
  if constexpr (MODE == 2) {
    Bp += (size_t)e * DFF_ * E_;
  } else if constexpr (MODE == 3) {
    Abase = Abh + (size_t)kz * 1024;
    Bp = Bw + (size_t)e * E_ * DFF_ + (size_t)kz * 1024;
    lda = DFF_;
    ldb = DFF_;
  }

  f32x4 acc[4][4];
#pragma unroll
  for (int i = 0; i < 4; i++)
#pragma unroll
    for (int j = 0; j < 4; j++) acc[i][j] = (f32x4){0.f, 0.f, 0.f, 0.f};

  const int wm = (wv >> 1) * 64, wn = (wv & 1) * 64;
  const int lr = lane & 15, lk = (lane >> 4) * 8;

  const int nK = Kdim / BK;
  for (int kt = 0; kt < nK; ++kt) {
    const int k0 = kt * BK;
    __syncthreads();
    // ---- stage A tile [128][BK] ----
    if constexpr (MODE == 0) {
#pragma unroll
      for (int i = 0; i < 4; i++) {
        int f = tid + i * 256, row = f >> 3, col = (f & 7) * 4;
        f32x4 v = *(const f32x4*)&Af32[(size_t)(m0 + row) * lda + k0 + col];
        bf16x4 hv, lv;
#pragma unroll
        for (int j = 0; j < 4; j++) { bf16_t hh, ll; split2(v[j], hh, ll); hv[j] = hh; lv[j] = ll; }
        *(bf16x4*)&Ah[row * LDST + col] = hv;
        *(bf16x4*)&Al[row * LDST + col] = lv;
      }
    } else if constexpr (MODE == 1) {
#pragma unroll
      for (int i = 0; i < 2; i++) {
        int f = tid + i * 256, row = f >> 2, col = (f & 3) * 8;
        *(bf16x8*)&Ah[row * LDST + col] = *(const bf16x8*)&Abh[(size_t)(m0 + row) * lda + k0 + col];
        *(bf16x8*)&Al[row * LDST + col] = *(const bf16x8*)&Abl[(size_t)(m0 + row) * lda + k0 + col];
      }
    } else {
#pragma unroll
      for (int i = 0; i < 4; i++) {
        int f = tid + i * 256, row = f >> 3, col = (f & 7) * 8;
        int src;
        if constexpr (MODE == 2) src = perm[m0 + row];  // padded entries -> 0
        else                     src = m0 + row;        // slot-major A
        *(bf16x8*)&Ah[row * LDST + col] = *(const bf16x8*)&Abase[(size_t)src * lda + k0 + col];
      }
    }
    // ---- stage B tile [128][BK] (always fp32 weights) ----
    {
      constexpr int ITER = (BK == 32) ? 4 : 8;
#pragma unroll
      for (int i = 0; i < ITER; i++) {
        int f = tid + i * 256;
        int row = (BK == 32) ? (f >> 3) : (f >> 4);
        int col = (BK == 32) ? ((f & 7) * 4) : ((f & 15) * 4);
        f32x4 v = *(const f32x4*)&Bp[(size_t)(n0 + row) * ldb + k0 + col];
        if constexpr (SPLIT) {
          bf16x4 hv, lv;
#pragma unroll
          for (int j = 0; j < 4; j++) { bf16_t hh, ll; split2(v[j], hh, ll); hv[j] = hh; lv[j] = ll; }
          *(bf16x4*)&Bh[row * LDST + col] = hv;
          *(bf16x4*)&Bl[row * LDST + col] = lv;
        } else {
          bf16x4 hv;
#pragma unroll
          for (int j = 0; j < 4; j++) hv[j] = (bf16_t)v[j];
          *(bf16x4*)&Bh[row * LDST + col] = hv;
        }
      }
    }
    __syncthreads();
    // ---- MFMA ----
#pragma unroll
    for (int kk = 0; kk < BK / 32; ++kk) {
      bf16x8 afh[4], afl[4];
#pragma unroll
      for (int fm = 0; fm < 4; fm++) {
        afh[fm] = *(const bf16x8*)&Ah[(wm + fm * 16 + lr) * LDST + kk * 32 + lk];
        if constexpr (SPLIT)
          afl[fm] = *(const bf16x8*)&Al[(wm + fm * 16 + lr) * LDST + kk * 32 + lk];
      }
#pragma unroll
      for (int fn = 0; fn < 4; fn++) {
        bf16x8 bfh = *(const bf16x8*)&Bh[(wn + fn * 16 + lr) * LDST + kk * 32 + lk];
        bf16x8 bfl;
        if constexpr (SPLIT)
          bfl = *(const bf16x8*)&Bl[(wn + fn * 16 + lr) * LDST + kk * 32 + lk];
#pragma unroll
        for (int fm = 0; fm < 4; fm++) {
          acc[fm][fn] = mfma16(afh[fm], bfh, acc[fm][fn]);
          if constexpr (SPLIT) {
            acc[fm][fn] = mfma16(afh[fm], bfl, acc[fm][fn]);
            acc[fm][fn] = mfma16(afl[fm], bfh, acc[fm][fn]);
          }
        }
      }
    }
  }
  // ---- epilogue.  C/D layout: col = lane&15, row = (lane>>4)*4 + reg ----
  const int lr4 = (lane >> 4) * 4;
#pragma unroll
  for (int fm = 0; fm < 4; fm++) {
#pragma unroll
    for (int fn = 0; fn < 4; fn++) {
#pragma unroll
      for (int r = 0; r < 4; r++) {
        float v = acc[fm][fn][r];
        int row = wm + fm * 16 + lr4 + r;
        int col = wn + fn * 16 + lr;
        if constexpr (MODE == 0) {
          int gm = m0 + row, gn = n0 + col;
          v += bias[gn];
          int sec = gn >> 10, ee = gn & 1023, hh = ee >> 6, dd = ee & 63;
          if (sec == 0) v *= 0.125f;  // 1/sqrt(64), applied after bias like ref
          int ss = gm >> 1, bb = gm & 1, bhp = bb * 16 + hh;
          size_t di = ((size_t)bhp * 1024 + ss) * 64 + dd;
          bf16_t oh, ol; split2(v, oh, ol);
          bf16_t* dh = (sec == 0) ? Qh : (sec == 1) ? Kh2 : Vh2;
          bf16_t* dl = (sec == 0) ? Ql : (sec == 1) ? Kl2 : Vl2;
          dh[di] = oh; dl[di] = ol;
        } else if constexpr (MODE == 1) {
          int gm = m0 + row, gn = n0 + col;
          v += bias[gn] + res[(size_t)gm * E_ + gn];
          Cf32[(size_t)gm * E_ + gn] = v;
        } else if constexpr (MODE == 2) {
          int slot = m0 + row, gn = n0 + col;
          v += bias[e * DFF_ + gn];
          v = 0.5f * v * (1.0f + erff(v * 0.70710678118654752440f));  // exact gelu
          Cbf[(size_t)slot * DFF_ + gn] = (bf16_t)v;
        } else {
          int slot = m0 + row, gn = n0 + col;
          Cf32[((size_t)kz * SLOTS_ + slot) * E_ + gn] = v;
        }
      }
    }
  }
}

// ---------------------------------------------------------------------------
// V transpose: [bh][s][d] -> [bh][d][s] (hi and lo), LDS-tiled, coalesced.
// ---------------------------------------------------------------------------
__launch_bounds__(256)
__global__ void vtrans_kernel(const bf16_t* vh, const bf16_t* vl,
                              bf16_t* vth, bf16_t* vtl) {
  const int bh = blockIdx.y, s0 = blockIdx.x * 64;
  const int tid = threadIdx.x;
  __shared__ bf16_t th[64][72];
  __shared__ bf16_t tl[64][72];
#pragma unroll
  for (int i = 0; i < 2; i++) {
    int f = tid + i * 256, r = f >> 3, c = (f & 7) * 8;
    size_t g = ((size_t)bh * 1024 + s0 + r) * 64 + c;
    *(bf16x8*)&th[r][c] = *(const bf16x8*)&vh[g];
    *(bf16x8*)&tl[r][c] = *(const bf16x8*)&vl[g];
  }
  __syncthreads();
#pragma unroll
  for (int i = 0; i < 2; i++) {
    int f = tid + i * 256, d = f >> 3, c2 = (f & 7) * 8;
    bf16x8 oh, ol;
#pragma unroll
    for (int j = 0; j < 8; j++) { oh[j] = th[c2 + j][d]; ol[j] = tl[c2 + j][d]; }
    size_t g = ((size_t)bh * 64 + d) * 1024 + s0 + c2;
    *(bf16x8*)&vth[g] = oh;
    *(bf16x8*)&vtl[g] = ol;
  }
}

// ---------------------------------------------------------------------------
// Flash attention, split-bf16.  Block = (q-tile of 64 rows) x (one bh).
// 4 waves; wave owns 16 q rows.  KV tiles of 64.  Online softmax in fp32.
// ---------------------------------------------------------------------------
__launch_bounds__(256)
__global__ void attn_kernel(const bf16_t* gqh, const bf16_t* gql,
                            const bf16_t* gkh, const bf16_t* gkl,
                            const bf16_t* gvth, const bf16_t* gvtl,
                            bf16_t* aoh, bf16_t* aol) {
  const int bh = blockIdx.y, q0 = blockIdx.x * 64;
  const int tid = threadIdx.x, lane = tid & 63, wv = tid >> 6;
  const int lr = lane & 15, lk = (lane >> 4) * 8, lr4 = (lane >> 4) * 4;
  extern __shared__ char smem[];
  bf16_t* Kh = (bf16_t*)smem;       // [64][72]
  bf16_t* Kl = Kh + 64 * 72;
  bf16_t* Vh = Kl + 64 * 72;        // transposed [d][t]
  bf16_t* Vl = Vh + 64 * 72;
  bf16_t* Ph = Vl + 64 * 72;        // [64][72], wave w owns rows [16w,16w+16)
  bf16_t* Pl = Ph + 64 * 72;

  // Q fragments (held in registers all kernel).  A row = lane&15.
  const size_t qbase = ((size_t)bh * 1024 + q0 + wv * 16 + lr) * 64;
  bf16x8 qfh[2], qfl[2];
  qfh[0] = *(const bf16x8*)&gqh[qbase + lk];
  qfh[1] = *(const bf16x8*)&gqh[qbase + 32 + lk];
  qfl[0] = *(const bf16x8*)&gql[qbase + lk];
  qfl[1] = *(const bf16x8*)&gql[qbase + 32 + lk];

  f32x4 oacc[4];
#pragma unroll
  for (int i = 0; i < 4; i++) oacc[i] = (f32x4){0.f, 0.f, 0.f, 0.f};
  float m_r[4], l_r[4];
#pragma unroll
  for (int r = 0; r < 4; r++) { m_r[r] = -INFINITY; l_r[r] = 0.f; }

  for (int t0 = 0; t0 < S_; t0 += 64) {
    __syncthreads();
    // stage K [t][d] and V^T [d][t] tiles
#pragma unroll
    for (int i = 0; i < 2; i++) {
      int f = tid + i * 256, r = f >> 3, c = (f & 7) * 8;
      size_t gk = ((size_t)bh * 1024 + t0 + r) * 64 + c;
      *(bf16x8*)&Kh[r * 72 + c] = *(const bf16x8*)&gkh[gk];
      *(bf16x8*)&Kl[r * 72 + c] = *(const bf16x8*)&gkl[gk];
      size_t gv = ((size_t)bh * 64 + r) * 1024 + t0 + c;
      *(bf16x8*)&Vh[r * 72 + c] = *(const bf16x8*)&gvth[gv];
      *(bf16x8*)&Vl[r * 72 + c] = *(const bf16x8*)&gvtl[gv];
    }
    __syncthreads();
    // QK^T (split, 3 terms)
    f32x4 sacc[4];
#pragma unroll
    for (int i = 0; i < 4; i++) sacc[i] = (f32x4){0.f, 0.f, 0.f, 0.f};
#pragma unroll
    for (int kk = 0; kk < 2; ++kk) {
#pragma unroll
      for (int fn = 0; fn < 4; ++fn) {
        bf16x8 kbh = *(const bf16x8*)&Kh[(fn * 16 + lr) * 72 + kk * 32 + lk];
        bf16x8 kbl = *(const bf16x8*)&Kl[(fn * 16 + lr) * 72 + kk * 32 + lk];
        sacc[fn] = mfma16(qfh[kk], kbh, sacc[fn]);
        sacc[fn] = mfma16(qfh[kk], kbl, sacc[fn]);
        sacc[fn] = mfma16(qfl[kk], kbh, sacc[fn]);
      }
    }
    // online softmax, rows = (lane>>4)*4 + r, cols spread over lane&15 x fn
#pragma unroll
    for (int r = 0; r < 4; r++) {
      float mx = fmaxf(fmaxf(sacc[0][r], sacc[1][r]), fmaxf(sacc[2][r], sacc[3][r]));
#pragma unroll
      for (int off = 1; off < 16; off <<= 1) mx = fmaxf(mx, __shfl_xor(mx, off));
      float mn = fmaxf(m_r[r], mx);
      float al = expf(m_r[r] - mn);   // first tile: exp(-inf)=0
      l_r[r] *= al;
#pragma unroll
      for (int fd = 0; fd < 4; fd++) oacc[fd][r] *= al;
      float ps = 0.f;
      int pr = wv * 16 + lr4 + r;
#pragma unroll
      for (int fn = 0; fn < 4; fn++) {
        float p = expf(sacc[fn][r] - mn);
        ps += p;
        bf16_t ph, pl; split2(p, ph, pl);
        Ph[pr * 72 + fn * 16 + lr] = ph;
        Pl[pr * 72 + fn * 16 + lr] = pl;
      }
#pragma unroll
      for (int off = 1; off < 16; off <<= 1) ps += __shfl_xor(ps, off);
      l_r[r] += ps;
      m_r[r] = mn;
    }
    __syncthreads();
    // PV (split, 3 terms).  A=P (k=t), B=V^T rows d.
#pragma unroll
    for (int kk = 0; kk < 2; kk++) {
      bf16x8 pah = *(const bf16x8*)&Ph[(wv * 16 + lr) * 72 + kk * 32 + lk];
      bf16x8 pal = *(const bf16x8*)&Pl[(wv * 16 + lr) * 72 + kk * 32 + lk];
#pragma unroll
      for (int fd = 0; fd < 4; fd++) {
        bf16x8 vbh = *(const bf16x8*)&Vh[(fd * 16 + lr) * 72 + kk * 32 + lk];
        bf16x8 vbl = *(const bf16x8*)&Vl[(fd * 16 + lr) * 72 + kk * 32 + lk];
        oacc[fd] = mfma16(pah, vbh, oacc[fd]);
        oacc[fd] = mfma16(pah, vbl, oacc[fd]);
        oacc[fd] = mfma16(pal, vbh, oacc[fd]);
      }
    }
  }
  // epilogue: O/l -> attn_out [token][E] hi/lo
  const int b = bh >> 4, h = bh & 15;
#pragma unroll
  for (int fd = 0; fd < 4; fd++) {
#pragma unroll
    for (int r = 0; r < 4; r++) {
      float v = oacc[fd][r] / l_r[r];
      int s = q0 + wv * 16 + lr4 + r;
      int d = fd * 16 + lr;
      size_t idx = ((size_t)(s * 2 + b)) * 1024 + h * 64 + d;
      bf16_t oh, ol; split2(v, oh, ol);
      aoh[idx] = oh;
      aol[idx] = ol;
    }
  }
}

// ---------------------------------------------------------------------------
// LN1: row LayerNorm over E=1024, writes f32 + bf16.
// ---------------------------------------------------------------------------
__launch_bounds__(256)
__global__ void ln_kernel(const float* in, const float* g, const float* bt,
                          float* outf, bf16_t* outb) {
  const int row = blockIdx.x, tid = threadIdx.x;
  f32x4 v = *(const f32x4*)&in[(size_t)row * 1024 + tid * 4];
  float s = v[0] + v[1] + v[2] + v[3];
  float q = v[0] * v[0] + v[1] * v[1] + v[2] * v[2] + v[3] * v[3];
#pragma unroll
  for (int off = 1; off < 64; off <<= 1) { s += __shfl_xor(s, off); q += __shfl_xor(q, off); }
  __shared__ float ss[4], qq[4];
  int wv = tid >> 6;
  if ((tid & 63) == 0) { ss[wv] = s; qq[wv] = q; }
  __syncthreads();
  s = ss[0] + ss[1] + ss[2] + ss[3];
  q = qq[0] + qq[1] + qq[2] + qq[3];
  float mu = s * (1.f / 1024.f);
  float var = q * (1.f / 1024.f) - mu * mu;
  float rs = rsqrtf(var + 1e-5f);
  f32x4 gg = *(const f32x4*)&g[tid * 4];
  f32x4 bb = *(const f32x4*)&bt[tid * 4];
  f32x4 o;
#pragma unroll
  for (int j = 0; j < 4; j++) o[j] = (v[j] - mu) * rs * gg[j] + bb[j];
  *(f32x4*)&outf[(size_t)row * 1024 + tid * 4] = o;
  bf16x4 ob;
#pragma unroll
  for (int j = 0; j < 4; j++) ob[j] = (bf16_t)o[j];
  *(bf16x4*)&outb[(size_t)row * 1024 + tid * 4] = ob;
}

// ---------------------------------------------------------------------------
// LN2 fused with split-K reduce: for token t, slot st=inv[t], expert e=eid[t]:
//   v = sum_kz partial[kz][st][:] + b2[e] + l1f[t]  -> LayerNorm -> out[t]
// ---------------------------------------------------------------------------
__launch_bounds__(256)
__global__ void ln2_kernel(const float* part, const float* l1f, const float* b2,
                           const int* eid, const int* inv, const float* g,
                           const float* bt, float* out) {
  const int t = blockIdx.x, tid = threadIdx.x;
  const int st = inv[t], e = eid[t];
  const int j = tid * 4;
  f32x4 v = *(const f32x4*)&part[(size_t)st * 1024 + j];
#pragma unroll
  for (int kz = 1; kz < SPLITK_; kz++) {
    f32x4 p = *(const f32x4*)&part[((size_t)kz * SLOTS_ + st) * 1024 + j];
#pragma unroll
    for (int i = 0; i < 4; i++) v[i] += p[i];
  }
  f32x4 bb2 = *(const f32x4*)&b2[e * 1024 + j];
  f32x4 rr = *(const f32x4*)&l1f[(size_t)t * 1024 + j];
#pragma unroll
  for (int i = 0; i < 4; i++) v[i] += bb2[i] + rr[i];

  float s = v[0] + v[1] + v[2] + v[3];
  float q = v[0] * v[0] + v[1] * v[1] + v[2] * v[2] + v[3] * v[3];
#pragma unroll
  for (int off = 1; off < 64; off <<= 1) { s += __shfl_xor(s, off); q += __shfl_xor(q, off); }
  __shared__ float ss[4], qq[4];
  int wv = tid >> 6;
  if ((tid & 63) == 0) { ss[wv] = s; qq[wv] = q; }
  __syncthreads();
  s = ss[0] + ss[1] + ss[2] + ss[3];
  q = qq[0] + qq[1] + qq[2] + qq[3];
  float mu = s * (1.f / 1024.f);
  float var = q * (1.f / 1024.f) - mu * mu;
  float rs = rsqrtf(var + 1e-5f);
  f32x4 gg = *(const f32x4*)&g[tid * 4];
  f32x4 bb = *(const f32x4*)&bt[tid * 4];
  f32x4 o;
#pragma unroll
  for (int jj = 0; jj < 4; jj++) o[jj] = (v[jj] - mu) * rs * gg[jj] + bb[jj];
  *(f32x4*)&out[(size_t)t * 1024 + j] = o;
}

// ---------------------------------------------------------------------------
// Gate: logits (fp32 dot), argmax (first max), per-expert counts.
// ---------------------------------------------------------------------------
__launch_bounds__(256)
__global__ void gate_kernel(const float* ln1f, const float* gw, const float* gb,
                            int* eid, int* cnt) {
  const int t = blockIdx.x * 4 + (threadIdx.x >> 6);
  const int lane = threadIdx.x & 63;
  float a[8] = {0, 0, 0, 0, 0, 0, 0, 0};
  for (int k0 = lane * 4; k0 < 1024; k0 += 256) {
    f32x4 xv = *(const f32x4*)&ln1f[(size_t)t * 1024 + k0];
#pragma unroll
    for (int ee = 0; ee < 8; ee++) {
      f32x4 wv4 = *(const f32x4*)&gw[ee * 1024 + k0];
      a[ee] += xv[0] * wv4[0] + xv[1] * wv4[1] + xv[2] * wv4[2] + xv[3] * wv4[3];
    }
  }
#pragma unroll
  for (int ee = 0; ee < 8; ee++)
#pragma unroll
    for (int off = 1; off < 64; off <<= 1) a[ee] += __shfl_xor(a[ee], off);
  if (lane == 0) {
    float best = a[0] + gb[0];
    int be = 0;
#pragma unroll
    for (int ee = 1; ee < 8; ee++) {
      float vv = a[ee] + gb[ee];
      if (vv > best) { best = vv; be = ee; }  // strict > : first-max, matches argmax
    }
    eid[t] = be;
    atomicAdd(&cnt[be], 1);
  }
}

__global__ void zero_kernel(int* cnt) {
  if (threadIdx.x < 8) cnt[threadIdx.x] = 0;
}

// offs: real prefix sums; offs_pad: 128-aligned prefix sums
__global__ void scan_kernel(const int* cnt, int* offs, int* offs_pad, int* cur) {
  if (threadIdx.x == 0) {
    int o = 0, op = 0;
    for (int e = 0; e < 8; e++) {
      offs[e] = o; offs_pad[e] = op;
      o += cnt[e]; op += (cnt[e] + 127) & ~127;
      cur[e] = 0;
    }
    offs[8] = o; offs_pad[8] = op;
  }
}

__global__ void scatter_kernel(const int* eid, const int* offs_pad, int* cur,
                               int* perm, int* inv) {
  int t = blockIdx.x * 256 + threadIdx.x;
  int ee = eid[t];
  int pos = atomicAdd(&cur[ee], 1);
  int slot = offs_pad[ee] + pos;
  perm[slot] = t;
  inv[t] = slot;
}

// ---------------------------------------------------------------------------
extern "C" void kernel_launch(void* const* d_in, const int* in_sizes, int n_in,
                              void* d_out, int out_size, void* d_ws, size_t ws_size,
                              hipStream_t stream) {
  const float* x    = (const float*)d_in[0];
  const float* ipw  = (const float*)d_in[1];
  const float* ipb  = (const float*)d_in[2];
  const float* opw  = (const float*)d_in[3];
  const float* opb  = (const float*)d_in[4];
  const float* ln1g = (const float*)d_in[5];
  const float* ln1b = (const float*)d_in[6];
  const float* ln2g = (const float*)d_in[7];
  const float* ln2b = (const float*)d_in[8];
  const float* gw   = (const float*)d_in[9];
  const float* gb   = (const float*)d_in[10];
  const float* w1   = (const float*)d_in[11];
  const float* b1   = (const float*)d_in[12];
  const float* w2   = (const float*)d_in[13];
  const float* b2   = (const float*)d_in[14];
  float* out = (float*)d_out;

  char* w = (char*)d_ws;
  auto alloc = [&](size_t n) { char* p = w; w += (n + 255) & ~(size_t)255; return p; };
  const size_t NBH = (size_t)32 * 1024 * 64;  // per Q/K/V buffer elems (2M)

  bf16_t* qh  = (bf16_t*)alloc(NBH * 2);
  bf16_t* ql  = (bf16_t*)alloc(NBH * 2);
  bf16_t* kh  = (bf16_t*)alloc(NBH * 2);
  bf16_t* kl  = (bf16_t*)alloc(NBH * 2);
  bf16_t* vh  = (bf16_t*)alloc(NBH * 2);
  bf16_t* vl  = (bf16_t*)alloc(NBH * 2);
  bf16_t* vth = (bf16_t*)alloc(NBH * 2);
  bf16_t* vtl = (bf16_t*)alloc(NBH * 2);
  bf16_t* aoh = (bf16_t*)alloc((size_t)T_ * E_ * 2);
  bf16_t* aol = (bf16_t*)alloc((size_t)T_ * E_ * 2);
  float*  pre1 = (float*)alloc((size_t)T_ * E_ * 4);
  bf16_t* l1b  = (bf16_t*)alloc((size_t)T_ * E_ * 2);
  float*  l1f  = (float*)alloc((size_t)T_ * E_ * 4);
  bf16_t* hbuf = (bf16_t*)alloc((size_t)SLOTS_ * DFF_ * 2);
  float*  part = (float*)alloc((size_t)SPLITK_ * SLOTS_ * E_ * 4);
  int* eid  = (int*)alloc(T_ * 4);
  int* cnt  = (int*)alloc(16 * 4);
  int* offs = (int*)alloc(16 * 4);
  int* offsp = (int*)alloc(16 * 4);
  int* cur  = (int*)alloc(16 * 4);
  int* perm = (int*)alloc(SLOTS_ * 4);
  int* inv  = (int*)alloc(T_ * 4);

  const dim3 blk(256);
  const int smemSplit  = 4 * 128 * 40 * 2;  // 40960
  const int smemSingle = 2 * 128 * 72 * 2;  // 36864
  const int smemAttn   = 6 * 64 * 72 * 2;   // 55296

  zero_kernel<<<1, 64, 0, stream>>>(cnt);
  hipMemsetAsync(perm, 0, SLOTS_ * 4, stream);  // padded perm entries -> token 0

  // 1) QKV projection (split) -> Q/K/V hi/lo in [bh][s][d]
  gemm_kernel<0><<<dim3(24, 16, 1), blk, smemSplit, stream>>>(
      x, nullptr, nullptr, ipw, ipb, nullptr, nullptr, nullptr,
      qh, ql, kh, kl, vh, vl, nullptr, nullptr, 1024);

  // 2) V transpose -> [bh][d][s]
  vtrans_kernel<<<dim3(16, 32), blk, 0, stream>>>(vh, vl, vth, vtl);

  // 3) flash attention -> attn_out hi/lo [token][E]
  attn_kernel<<<dim3(16, 32), blk, smemAttn, stream>>>(qh, ql, kh, kl, vth, vtl, aoh, aol);

  // 4) out_proj + bias + residual -> pre1
  gemm_kernel<1><<<dim3(8, 16, 1), blk, smemSplit, stream>>>(
      nullptr, aoh, aol, opw, opb, x, pre1, nullptr,
      nullptr, nullptr, nullptr, nullptr, nullptr, nullptr, nullptr, nullptr, 1024);

  // 5) LN1 -> l1f (f32) + l1b (bf16)
  ln_kernel<<<dim3(T_), blk, 0, stream>>>(pre1, ln1g, ln1b, l1f, l1b);

  // 6) gate + routing (padded 128-aligned slots)
  gate_kernel<<<dim3(T_ / 4), blk, 0, stream>>>(l1f, gw, gb, eid, cnt);
  scan_kernel<<<1, 64, 0, stream>>>(cnt, offs, offsp, cur);
  scatter_kernel<<<dim3(T_ / 256), blk, 0, stream>>>(eid, offsp, cur, perm, inv);

  // 7) expert FFN up: h = gelu(t @ w1^T + b1) -> hbuf (bf16, slot-major)
  gemm_kernel<2><<<dim3(32, 24, 1), blk, smemSingle, stream>>>(
      nullptr, l1b, nullptr, w1, b1, nullptr, nullptr, hbuf,
      nullptr, nullptr, nullptr, nullptr, nullptr, nullptr, offsp, perm, 1024);

  // 8) expert FFN down, split-K -> fp32 partials [kz][slot][E]
  gemm_kernel<3><<<dim3(8, 24, SPLITK_), blk, smemSingle, stream>>>(
      nullptr, hbuf, nullptr, w2, nullptr, nullptr, part, nullptr,
      nullptr, nullptr, nullptr, nullptr, nullptr, nullptr, offsp, perm, 1024);

  // 9) LN2 (fused split-K reduce + b2 + residual) -> d_out
  ln2_kernel<<<dim3(T_), blk, 0, stream>>>(part, l1f, b2, eid, inv, ln2g, ln2b, out);

  (void)in_sizes; (void)n_in; (void)out_size; (void)ws_size;
}

// Round 3
// 395.193 us; speedup vs baseline: 1.3926x; 1.1320x over previous
//
#include <hip/hip_runtime.h>
#include <hip/hip_bf16.h>
#include <math.h>

#define DI __device__ __forceinline__

typedef __bf16 bf16_t;
typedef bf16_t bf16x8 __attribute__((ext_vector_type(8)));
typedef bf16_t bf16x4 __attribute__((ext_vector_type(4)));
typedef float f32x4 __attribute__((ext_vector_type(4)));

constexpr int S_ = 1024, B_ = 2, E_ = 1024, H_ = 16, HD_ = 64;
constexpr int T_ = S_ * B_;      // 2048 tokens
constexpr int DFF_ = 4096, NE_ = 8;
constexpr int SLOTS_ = 3072;     // padded slot capacity
constexpr int SPLITK_ = 4;       // K-split for MoE down-proj

DI f32x4 mfma16(bf16x8 a, bf16x8 b, f32x4 c) {
  return __builtin_amdgcn_mfma_f32_16x16x32_bf16(a, b, c, 0, 0, 0);
}

// split fp32 into hi/lo bf16 (v ~= hi + lo, residual ~2^-18 relative)
DI void split2(float v, bf16_t& h, bf16_t& l) {
  h = (bf16_t)v;
  l = (bf16_t)(v - (float)h);
}

// ---------------------------------------------------------------------------
// 128x128-tile MFMA GEMM, double-buffered LDS + register prefetch,
// XOR-swizzled unpadded LDS (row byte addr ^= (row&7)<<4).
// C[m,n] = sum_k A[m,k]*B[n,k]  (B row-major [N][K]).
// MODE 0: QKV     A=x fp32 (split),  epi: +bias, scale Q, scatter hi/lo QKV
// MODE 1: OUTPROJ A=attn hi/lo bf16 (split), epi: +bias +x residual -> f32
// MODE 2: MOE1    A=ln1 bf16 gathered via padded perm, epi: +b1, gelu -> bf16
// MODE 3: MOE2    A=hbuf bf16 slot-major, split-K over z, epi: fp32 partials
// ---------------------------------------------------------------------------
template <int MODE>
__launch_bounds__(256, 2)
__global__ void gemm_kernel(const float* Af32, const bf16_t* Abh, const bf16_t* Abl,
                            const float* Bw, const float* bias, const float* res,
                            float* Cf32, bf16_t* Cbf,
                            bf16_t* Qh, bf16_t* Ql, bf16_t* Kh2, bf16_t* Kl2,
                            bf16_t* Vh2, bf16_t* Vl2,
                            const int* offs_pad, const int* perm, int Kdim) {
  constexpr bool SPLIT = (MODE <= 1);
  constexpr int BK = SPLIT ? 32 : 64;
  constexpr int RB = BK * 2;           // row bytes (unpadded)
  constexpr int MATB = 128 * RB;       // one matrix tile, bytes
  constexpr int NMAT = SPLIT ? 4 : 2;  // Ah,Al,Bh,Bl | Ah,Bh
  constexpr int BUFB = NMAT * MATB;    // 32768; x2 buffers = 65536 total
  extern __shared__ char smem[];

  const int tid = threadIdx.x, lane = tid & 63, wv = tid >> 6;
  const int n0 = blockIdx.x * 128, m0 = blockIdx.y * 128;

  int e = 0;
  if constexpr (MODE >= 2) {
    if (m0 >= offs_pad[8]) return;  // uniform early exit, before any barrier
#pragma unroll
    for (int i = 1; i < 8; i++) e += (m0 >= offs_pad[i]);
  }
  const int kz = (MODE == 3) ? blockIdx.z : 0;

  const bf16_t* Abase = Abh;
  const float* Bp = Bw;
  size_t lda = (size_t)Kdim, ldb = (size_t)Kdim;
  if constexpr (MODE == 2) {
    Bp += (size_t)e * DFF_ * E_;
  } else if constexpr (MODE == 3) {
    Abase = Abh + (size_t)kz * 1024;
    Bp = Bw + (size_t)e * E_ * DFF_ + (size_t)kz * 1024;
    lda = DFF_;
    ldb = DFF_;
  }

  // hoisted A-row gather indices (MODE>=2)
  int asrc[4];
  if constexpr (MODE >= 2) {
#pragma unroll
    for (int i = 0; i < 4; i++) {
      int row = m0 + (tid >> 3) + i * 32;
      asrc[i] = (MODE == 2) ? perm[row] : row;
    }
  }

  // LDS byte-offset swizzle (store & read identical)
  auto SW = [&](int row, int cb) { return (row * RB + cb) ^ ((row & 7) << 4); };

  // staging registers
  f32x4 ra[(MODE == 0) ? 4 : 1];
  bf16x8 rah[(MODE == 1) ? 2 : 4];
  bf16x8 ral[(MODE == 1) ? 2 : 1];
  f32x4 rb[SPLIT ? 4 : 8];

  auto LOADA = [&](int k0) {
    if constexpr (MODE == 0) {
#pragma unroll
      for (int i = 0; i < 4; i++)
        ra[i] = *(const f32x4*)&Af32[(size_t)(m0 + (tid >> 3) + i * 32) * lda + k0 + (tid & 7) * 4];
    } else if constexpr (MODE == 1) {
#pragma unroll
      for (int i = 0; i < 2; i++) {
        size_t g = (size_t)(m0 + (tid >> 2) + i * 64) * lda + k0 + (tid & 3) * 8;
        rah[i] = *(const bf16x8*)&Abh[g];
        ral[i] = *(const bf16x8*)&Abl[g];
      }
    } else {
#pragma unroll
      for (int i = 0; i < 4; i++)
        rah[i] = *(const bf16x8*)&Abase[(size_t)asrc[i] * lda + k0 + (tid & 7) * 8];
    }
  };
  auto LOADB = [&](int k0) {
    if constexpr (SPLIT) {
#pragma unroll
      for (int i = 0; i < 4; i++)
        rb[i] = *(const f32x4*)&Bp[(size_t)(n0 + (tid >> 3) + i * 32) * ldb + k0 + (tid & 7) * 4];
    } else {
#pragma unroll
      for (int i = 0; i < 8; i++)
        rb[i] = *(const f32x4*)&Bp[(size_t)(n0 + (tid >> 4) + i * 16) * ldb + k0 + (tid & 15) * 4];
    }
  };
  auto STORE = [&](char* base) {
    char* Ahb = base;
    char* Alb = base + (SPLIT ? MATB : 0);
    char* Bhb = base + (SPLIT ? 2 : 1) * MATB;
    char* Blb = Bhb + (SPLIT ? MATB : 0);
    if constexpr (MODE == 0) {
#pragma unroll
      for (int i = 0; i < 4; i++) {
        int row = (tid >> 3) + i * 32, cb = (tid & 7) * 8;
        bf16x4 hv, lv;
#pragma unroll
        for (int j = 0; j < 4; j++) { bf16_t h, l; split2(ra[i][j], h, l); hv[j] = h; lv[j] = l; }
        *(bf16x4*)(Ahb + SW(row, cb)) = hv;
        *(bf16x4*)(Alb + SW(row, cb)) = lv;
      }
    } else if constexpr (MODE == 1) {
#pragma unroll
      for (int i = 0; i < 2; i++) {
        int row = (tid >> 2) + i * 64, cb = (tid & 3) * 16;
        *(bf16x8*)(Ahb + SW(row, cb)) = rah[i];
        *(bf16x8*)(Alb + SW(row, cb)) = ral[i];
      }
    } else {
#pragma unroll
      for (int i = 0; i < 4; i++) {
        int row = (tid >> 3) + i * 32, cb = (tid & 7) * 16;
        *(bf16x8*)(Ahb + SW(row, cb)) = rah[i];
      }
    }
    if constexpr (SPLIT) {
#pragma unroll
      for (int i = 0; i < 4; i++) {
        int row = (tid >> 3) + i * 32, cb = (tid & 7) * 8;
        bf16x4 hv, lv;
#pragma unroll
        for (int j = 0; j < 4; j++) { bf16_t h, l; split2(rb[i][j], h, l); hv[j] = h; lv[j] = l; }
        *(bf16x4*)(Bhb + SW(row, cb)) = hv;
        *(bf16x4*)(Blb + SW(row, cb)) = lv;
      }
    } else {
#pragma unroll
      for (int i = 0; i < 8; i++) {
        int row = (tid >> 4) + i * 16, cb = (tid & 15) * 8;
        bf16x4 hv;
#pragma unroll
        for (int j = 0; j < 4; j++) hv[j] = (bf16_t)rb[i][j];
        *(bf16x4*)(Bhb + SW(row, cb)) = hv;
      }
    }
  };

  f32x4 acc[4][4];
#pragma unroll
  for (int i = 0; i < 4; i++)
#pragma unroll
    for (int j = 0; j < 4; j++) acc[i][j] = (f32x4){0.f, 0.f, 0.f, 0.f};

  const int wm = (wv >> 1) * 64, wn = (wv & 1) * 64;
  const int lr = lane & 15, lk = (lane >> 4) * 8;

  auto COMPUTE = [&](const char* base) {
    const char* Ahb = base;
    const char* Alb = base + (SPLIT ? MATB : 0);
    const char* Bhb = base + (SPLIT ? 2 : 1) * MATB;
    const char* Blb = Bhb + (SPLIT ? MATB : 0);
#pragma unroll
    for (int kk = 0; kk < BK / 32; ++kk) {
      const int cb = (kk * 32 + lk) * 2;
      bf16x8 afh[4], afl[4];
#pragma unroll
      for (int fm = 0; fm < 4; fm++) {
        afh[fm] = *(const bf16x8*)(Ahb + SW(wm + fm * 16 + lr, cb));
        if constexpr (SPLIT)
          afl[fm] = *(const bf16x8*)(Alb + SW(wm + fm * 16 + lr, cb));
      }
#pragma unroll
      for (int fn = 0; fn < 4; fn++) {
        bf16x8 bfh = *(const bf16x8*)(Bhb + SW(wn + fn * 16 + lr, cb));
        bf16x8 bfl;
        if constexpr (SPLIT)
          bfl = *(const bf16x8*)(Blb + SW(wn + fn * 16 + lr, cb));
#pragma unroll
        for (int fm = 0; fm < 4; fm++) {
          acc[fm][fn] = mfma16(afh[fm], bfh, acc[fm][fn]);
          if constexpr (SPLIT) {
            acc[fm][fn] = mfma16(afh[fm], bfl, acc[fm][fn]);
            acc[fm][fn] = mfma16(afl[fm], bfh, acc[fm][fn]);
          }
        }
      }
    }
  };

  // ---- pipelined main loop: load(k+1) || mfma(k), store(k+1), barrier ----
  const int nK = Kdim / BK;
  LOADA(0); LOADB(0);
  STORE(smem);
  __syncthreads();
  int buf = 0;
  for (int kt = 0; kt < nK; ++kt) {
    const bool more = (kt + 1 < nK);
    if (more) { LOADA((kt + 1) * BK); LOADB((kt + 1) * BK); }
    COMPUTE(smem + buf * BUFB);
    if (more) {
      STORE(smem + (buf ^ 1) * BUFB);
      __syncthreads();
      buf ^= 1;
    }
  }

  // ---- epilogue.  C/D layout: col = lane&15, row = (lane>>4)*4 + reg ----
  const int lr4 = (lane >> 4) * 4;
#pragma unroll
  for (int fm = 0; fm < 4; fm++) {
#pragma unroll
    for (int fn = 0; fn < 4; fn++) {
#pragma unroll
      for (int r = 0; r < 4; r++) {
        float v = acc[fm][fn][r];
        int row = wm + fm * 16 + lr4 + r;
        int col = wn + fn * 16 + lr;
        if constexpr (MODE == 0) {
          int gm = m0 + row, gn = n0 + col;
          v += bias[gn];
          int sec = gn >> 10, ee = gn & 1023, hh = ee >> 6, dd = ee & 63;
          if (sec == 0) v *= 0.125f;  // 1/sqrt(64), applied after bias like ref
          int ss = gm >> 1, bb = gm & 1, bhp = bb * 16 + hh;
          size_t di = ((size_t)bhp * 1024 + ss) * 64 + dd;
          bf16_t oh, ol; split2(v, oh, ol);
          bf16_t* dh = (sec == 0) ? Qh : (sec == 1) ? Kh2 : Vh2;
          bf16_t* dl = (sec == 0) ? Ql : (sec == 1) ? Kl2 : Vl2;
          dh[di] = oh; dl[di] = ol;
        } else if constexpr (MODE == 1) {
          int gm = m0 + row, gn = n0 + col;
          v += bias[gn] + res[(size_t)gm * E_ + gn];
          Cf32[(size_t)gm * E_ + gn] = v;
        } else if constexpr (MODE == 2) {
          int slot = m0 + row, gn = n0 + col;
          v += bias[e * DFF_ + gn];
          v = 0.5f * v * (1.0f + erff(v * 0.70710678118654752440f));  // exact gelu
          Cbf[(size_t)slot * DFF_ + gn] = (bf16_t)v;
        } else {
          int slot = m0 + row, gn = n0 + col;
          Cf32[((size_t)kz * SLOTS_ + slot) * E_ + gn] = v;
        }
      }
    }
  }
}

// ---------------------------------------------------------------------------
// V transpose: [bh][s][d] -> [bh][d][s] (hi and lo), LDS-tiled, coalesced.
// ---------------------------------------------------------------------------
__launch_bounds__(256)
__global__ void vtrans_kernel(const bf16_t* vh, const bf16_t* vl,
                              bf16_t* vth, bf16_t* vtl) {
  const int bh = blockIdx.y, s0 = blockIdx.x * 64;
  const int tid = threadIdx.x;
  __shared__ bf16_t th[64][72];
  __shared__ bf16_t tl[64][72];
#pragma unroll
  for (int i = 0; i < 2; i++) {
    int f = tid + i * 256, r = f >> 3, c = (f & 7) * 8;
    size_t g = ((size_t)bh * 1024 + s0 + r) * 64 + c;
    *(bf16x8*)&th[r][c] = *(const bf16x8*)&vh[g];
    *(bf16x8*)&tl[r][c] = *(const bf16x8*)&vl[g];
  }
  __syncthreads();
#pragma unroll
  for (int i = 0; i < 2; i++) {
    int f = tid + i * 256, d = f >> 3, c2 = (f & 7) * 8;
    bf16x8 oh, ol;
#pragma unroll
    for (int j = 0; j < 8; j++) { oh[j] = th[c2 + j][d]; ol[j] = tl[c2 + j][d]; }
    size_t g = ((size_t)bh * 64 + d) * 1024 + s0 + c2;
    *(bf16x8*)&vth[g] = oh;
    *(bf16x8*)&vtl[g] = ol;
  }
}

// ---------------------------------------------------------------------------
// Flash attention, split-bf16.  Block = (q-tile of 64 rows) x (one bh).
// ---------------------------------------------------------------------------
__launch_bounds__(256)
__global__ void attn_kernel(const bf16_t* gqh, const bf16_t* gql,
                            const bf16_t* gkh, const bf16_t* gkl,
                            const bf16_t* gvth, const bf16_t* gvtl,
                            bf16_t* aoh, bf16_t* aol) {
  const int bh = blockIdx.y, q0 = blockIdx.x * 64;
  const int tid = threadIdx.x, lane = tid & 63, wv = tid >> 6;
  const int lr = lane & 15, lk = (lane >> 4) * 8, lr4 = (lane >> 4) * 4;
  extern __shared__ char smem[];
  bf16_t* Kh = (bf16_t*)smem;       // [64][72]
  bf16_t* Kl = Kh + 64 * 72;
  bf16_t* Vh = Kl + 64 * 72;        // transposed [d][t]
  bf16_t* Vl = Vh + 64 * 72;
  bf16_t* Ph = Vl + 64 * 72;        // [64][72]
  bf16_t* Pl = Ph + 64 * 72;

  const size_t qbase = ((size_t)bh * 1024 + q0 + wv * 16 + lr) * 64;
  bf16x8 qfh[2], qfl[2];
  qfh[0] = *(const bf16x8*)&gqh[qbase + lk];
  qfh[1] = *(const bf16x8*)&gqh[qbase + 32 + lk];
  qfl[0] = *(const bf16x8*)&gql[qbase + lk];
  qfl[1] = *(const bf16x8*)&gql[qbase + 32 + lk];

  f32x4 oacc[4];
#pragma unroll
  for (int i = 0; i < 4; i++) oacc[i] = (f32x4){0.f, 0.f, 0.f, 0.f};
  float m_r[4], l_r[4];
#pragma unroll
  for (int r = 0; r < 4; r++) { m_r[r] = -INFINITY; l_r[r] = 0.f; }

  for (int t0 = 0; t0 < S_; t0 += 64) {
    __syncthreads();
#pragma unroll
    for (int i = 0; i < 2; i++) {
      int f = tid + i * 256, r = f >> 3, c = (f & 7) * 8;
      size_t gk = ((size_t)bh * 1024 + t0 + r) * 64 + c;
      *(bf16x8*)&Kh[r * 72 + c] = *(const bf16x8*)&gkh[gk];
      *(bf16x8*)&Kl[r * 72 + c] = *(const bf16x8*)&gkl[gk];
      size_t gv = ((size_t)bh * 64 + r) * 1024 + t0 + c;
      *(bf16x8*)&Vh[r * 72 + c] = *(const bf16x8*)&gvth[gv];
      *(bf16x8*)&Vl[r * 72 + c] = *(const bf16x8*)&gvtl[gv];
    }
    __syncthreads();
    f32x4 sacc[4];
#pragma unroll
    for (int i = 0; i < 4; i++) sacc[i] = (f32x4){0.f, 0.f, 0.f, 0.f};
#pragma unroll
    for (int kk = 0; kk < 2; ++kk) {
#pragma unroll
      for (int fn = 0; fn < 4; ++fn) {
        bf16x8 kbh = *(const bf16x8*)&Kh[(fn * 16 + lr) * 72 + kk * 32 + lk];
        bf16x8 kbl = *(const bf16x8*)&Kl[(fn * 16 + lr) * 72 + kk * 32 + lk];
        sacc[fn] = mfma16(qfh[kk], kbh, sacc[fn]);
        sacc[fn] = mfma16(qfh[kk], kbl, sacc[fn]);
        sacc[fn] = mfma16(qfl[kk], kbh, sacc[fn]);
      }
    }
#pragma unroll
    for (int r = 0; r < 4; r++) {
      float mx = fmaxf(fmaxf(sacc[0][r], sacc[1][r]), fmaxf(sacc[2][r], sacc[3][r]));
#pragma unroll
      for (int off = 1; off < 16; off <<= 1) mx = fmaxf(mx, __shfl_xor(mx, off));
      float mn = fmaxf(m_r[r], mx);
      float al = expf(m_r[r] - mn);
      l_r[r] *= al;
#pragma unroll
      for (int fd = 0; fd < 4; fd++) oacc[fd][r] *= al;
      float ps = 0.f;
      int pr = wv * 16 + lr4 + r;
#pragma unroll
      for (int fn = 0; fn < 4; fn++) {
        float p = expf(sacc[fn][r] - mn);
        ps += p;
        bf16_t ph, pl; split2(p, ph, pl);
        Ph[pr * 72 + fn * 16 + lr] = ph;
        Pl[pr * 72 + fn * 16 + lr] = pl;
      }
#pragma unroll
      for (int off = 1; off < 16; off <<= 1) ps += __shfl_xor(ps, off);
      l_r[r] += ps;
      m_r[r] = mn;
    }
    __syncthreads();
#pragma unroll
    for (int kk = 0; kk < 2; kk++) {
      bf16x8 pah = *(const bf16x8*)&Ph[(wv * 16 + lr) * 72 + kk * 32 + lk];
      bf16x8 pal = *(const bf16x8*)&Pl[(wv * 16 + lr) * 72 + kk * 32 + lk];
#pragma unroll
      for (int fd = 0; fd < 4; fd++) {
        bf16x8 vbh = *(const bf16x8*)&Vh[(fd * 16 + lr) * 72 + kk * 32 + lk];
        bf16x8 vbl = *(const bf16x8*)&Vl[(fd * 16 + lr) * 72 + kk * 32 + lk];
        oacc[fd] = mfma16(pah, vbh, oacc[fd]);
        oacc[fd] = mfma16(pah, vbl, oacc[fd]);
        oacc[fd] = mfma16(pal, vbh, oacc[fd]);
      }
    }
  }
  const int b = bh >> 4, h = bh & 15;
#pragma unroll
  for (int fd = 0; fd < 4; fd++) {
#pragma unroll
    for (int r = 0; r < 4; r++) {
      float v = oacc[fd][r] / l_r[r];
      int s = q0 + wv * 16 + lr4 + r;
      int d = fd * 16 + lr;
      size_t idx = ((size_t)(s * 2 + b)) * 1024 + h * 64 + d;
      bf16_t oh, ol; split2(v, oh, ol);
      aoh[idx] = oh;
      aol[idx] = ol;
    }
  }
}

// ---------------------------------------------------------------------------
// LN1: row LayerNorm over E=1024, writes f32 + bf16.
// ---------------------------------------------------------------------------
__launch_bounds__(256)
__global__ void ln_kernel(const float* in, const float* g, const float* bt,
                          float* outf, bf16_t* outb) {
  const int row = blockIdx.x, tid = threadIdx.x;
  f32x4 v = *(const f32x4*)&in[(size_t)row * 1024 + tid * 4];
  float s = v[0] + v[1] + v[2] + v[3];
  float q = v[0] * v[0] + v[1] * v[1] + v[2] * v[2] + v[3] * v[3];
#pragma unroll
  for (int off = 1; off < 64; off <<= 1) { s += __shfl_xor(s, off); q += __shfl_xor(q, off); }
  __shared__ float ss[4], qq[4];
  int wv = tid >> 6;
  if ((tid & 63) == 0) { ss[wv] = s; qq[wv] = q; }
  __syncthreads();
  s = ss[0] + ss[1] + ss[2] + ss[3];
  q = qq[0] + qq[1] + qq[2] + qq[3];
  float mu = s * (1.f / 1024.f);
  float var = q * (1.f / 1024.f) - mu * mu;
  float rs = rsqrtf(var + 1e-5f);
  f32x4 gg = *(const f32x4*)&g[tid * 4];
  f32x4 bb = *(const f32x4*)&bt[tid * 4];
  f32x4 o;
#pragma unroll
  for (int j = 0; j < 4; j++) o[j] = (v[j] - mu) * rs * gg[j] + bb[j];
  *(f32x4*)&outf[(size_t)row * 1024 + tid * 4] = o;
  bf16x4 ob;
#pragma unroll
  for (int j = 0; j < 4; j++) ob[j] = (bf16_t)o[j];
  *(bf16x4*)&outb[(size_t)row * 1024 + tid * 4] = ob;
}

// ---------------------------------------------------------------------------
// LN2 fused with split-K reduce + b2 + residual.
// ---------------------------------------------------------------------------
__launch_bounds__(256)
__global__ void ln2_kernel(const float* part, const float* l1f, const float* b2,
                           const int* eid, const int* inv, const float* g,
                           const float* bt, float* out) {
  const int t = blockIdx.x, tid = threadIdx.x;
  const int st = inv[t], e = eid[t];
  const int j = tid * 4;
  f32x4 v = *(const f32x4*)&part[(size_t)st * 1024 + j];
#pragma unroll
  for (int kz = 1; kz < SPLITK_; kz++) {
    f32x4 p = *(const f32x4*)&part[((size_t)kz * SLOTS_ + st) * 1024 + j];
#pragma unroll
    for (int i = 0; i < 4; i++) v[i] += p[i];
  }
  f32x4 bb2 = *(const f32x4*)&b2[e * 1024 + j];
  f32x4 rr = *(const f32x4*)&l1f[(size_t)t * 1024 + j];
#pragma unroll
  for (int i = 0; i < 4; i++) v[i] += bb2[i] + rr[i];

  float s = v[0] + v[1] + v[2] + v[3];
  float q = v[0] * v[0] + v[1] * v[1] + v[2] * v[2] + v[3] * v[3];
#pragma unroll
  for (int off = 1; off < 64; off <<= 1) { s += __shfl_xor(s, off); q += __shfl_xor(q, off); }
  __shared__ float ss[4], qq[4];
  int wv = tid >> 6;
  if ((tid & 63) == 0) { ss[wv] = s; qq[wv] = q; }
  __syncthreads();
  s = ss[0] + ss[1] + ss[2] + ss[3];
  q = qq[0] + qq[1] + qq[2] + qq[3];
  float mu = s * (1.f / 1024.f);
  float var = q * (1.f / 1024.f) - mu * mu;
  float rs = rsqrtf(var + 1e-5f);
  f32x4 gg = *(const f32x4*)&g[tid * 4];
  f32x4 bb = *(const f32x4*)&bt[tid * 4];
  f32x4 o;
#pragma unroll
  for (int jj = 0; jj < 4; jj++) o[jj] = (v[jj] - mu) * rs * gg[jj] + bb[jj];
  *(f32x4*)&out[(size_t)t * 1024 + j] = o;
}

// ---------------------------------------------------------------------------
// Gate: fp32 logits, argmax (first max), per-expert counts.
// ---------------------------------------------------------------------------
__launch_bounds__(256)
__global__ void gate_kernel(const float* ln1f, const float* gw, const float* gb,
                            int* eid, int* cnt) {
  const int t = blockIdx.x * 4 + (threadIdx.x >> 6);
  const int lane = threadIdx.x & 63;
  float a[8] = {0, 0, 0, 0, 0, 0, 0, 0};
  for (int k0 = lane * 4; k0 < 1024; k0 += 256) {
    f32x4 xv = *(const f32x4*)&ln1f[(size_t)t * 1024 + k0];
#pragma unroll
    for (int ee = 0; ee < 8; ee++) {
      f32x4 wv4 = *(const f32x4*)&gw[ee * 1024 + k0];
      a[ee] += xv[0] * wv4[0] + xv[1] * wv4[1] + xv[2] * wv4[2] + xv[3] * wv4[3];
    }
  }
#pragma unroll
  for (int ee = 0; ee < 8; ee++)
#pragma unroll
    for (int off = 1; off < 64; off <<= 1) a[ee] += __shfl_xor(a[ee], off);
  if (lane == 0) {
    float best = a[0] + gb[0];
    int be = 0;
#pragma unroll
    for (int ee = 1; ee < 8; ee++) {
      float vv = a[ee] + gb[ee];
      if (vv > best) { best = vv; be = ee; }
    }
    eid[t] = be;
    atomicAdd(&cnt[be], 1);
  }
}

__global__ void zero_kernel(int* cnt) {
  if (threadIdx.x < 8) cnt[threadIdx.x] = 0;
}

__global__ void scan_kernel(const int* cnt, int* offs, int* offs_pad, int* cur) {
  if (threadIdx.x == 0) {
    int o = 0, op = 0;
    for (int e = 0; e < 8; e++) {
      offs[e] = o; offs_pad[e] = op;
      o += cnt[e]; op += (cnt[e] + 127) & ~127;
      cur[e] = 0;
    }
    offs[8] = o; offs_pad[8] = op;
  }
}

__global__ void scatter_kernel(const int* eid, const int* offs_pad, int* cur,
                               int* perm, int* inv) {
  int t = blockIdx.x * 256 + threadIdx.x;
  int ee = eid[t];
  int pos = atomicAdd(&cur[ee], 1);
  int slot = offs_pad[ee] + pos;
  perm[slot] = t;
  inv[t] = slot;
}

// ---------------------------------------------------------------------------
extern "C" void kernel_launch(void* const* d_in, const int* in_sizes, int n_in,
                              void* d_out, int out_size, void* d_ws, size_t ws_size,
                              hipStream_t stream) {
  const float* x    = (const float*)d_in[0];
  const float* ipw  = (const float*)d_in[1];
  const float* ipb  = (const float*)d_in[2];
  const float* opw  = (const float*)d_in[3];
  const float* opb  = (const float*)d_in[4];
  const float* ln1g = (const float*)d_in[5];
  const float* ln1b = (const float*)d_in[6];
  const float* ln2g = (const float*)d_in[7];
  const float* ln2b = (const float*)d_in[8];
  const float* gw   = (const float*)d_in[9];
  const float* gb   = (const float*)d_in[10];
  const float* w1   = (const float*)d_in[11];
  const float* b1   = (const float*)d_in[12];
  const float* w2   = (const float*)d_in[13];
  const float* b2   = (const float*)d_in[14];
  float* out = (float*)d_out;

  char* w = (char*)d_ws;
  auto alloc = [&](size_t n) { char* p = w; w += (n + 255) & ~(size_t)255; return p; };
  const size_t NBH = (size_t)32 * 1024 * 64;

  bf16_t* qh  = (bf16_t*)alloc(NBH * 2);
  bf16_t* ql  = (bf16_t*)alloc(NBH * 2);
  bf16_t* kh  = (bf16_t*)alloc(NBH * 2);
  bf16_t* kl  = (bf16_t*)alloc(NBH * 2);
  bf16_t* vh  = (bf16_t*)alloc(NBH * 2);
  bf16_t* vl  = (bf16_t*)alloc(NBH * 2);
  bf16_t* vth = (bf16_t*)alloc(NBH * 2);
  bf16_t* vtl = (bf16_t*)alloc(NBH * 2);
  bf16_t* aoh = (bf16_t*)alloc((size_t)T_ * E_ * 2);
  bf16_t* aol = (bf16_t*)alloc((size_t)T_ * E_ * 2);
  float*  pre1 = (float*)alloc((size_t)T_ * E_ * 4);
  bf16_t* l1b  = (bf16_t*)alloc((size_t)T_ * E_ * 2);
  float*  l1f  = (float*)alloc((size_t)T_ * E_ * 4);
  bf16_t* hbuf = (bf16_t*)alloc((size_t)SLOTS_ * DFF_ * 2);
  float*  part = (float*)alloc((size_t)SPLITK_ * SLOTS_ * E_ * 4);
  int* eid  = (int*)alloc(T_ * 4);
  int* cnt  = (int*)alloc(16 * 4);
  int* offs = (int*)alloc(16 * 4);
  int* offsp = (int*)alloc(16 * 4);
  int* cur  = (int*)alloc(16 * 4);
  int* perm = (int*)alloc(SLOTS_ * 4);
  int* inv  = (int*)alloc(T_ * 4);

  const dim3 blk(256);
  const int smemGemm = 65536;           // 2 x 32768-byte double buffers
  const int smemAttn = 6 * 64 * 72 * 2; // 55296

  zero_kernel<<<1, 64, 0, stream>>>(cnt);
  hipMemsetAsync(perm, 0, SLOTS_ * 4, stream);  // padded perm entries -> token 0

  // 1) QKV projection (split) -> Q/K/V hi/lo in [bh][s][d]
  gemm_kernel<0><<<dim3(24, 16, 1), blk, smemGemm, stream>>>(
      x, nullptr, nullptr, ipw, ipb, nullptr, nullptr, nullptr,
      qh, ql, kh, kl, vh, vl, nullptr, nullptr, 1024);

  // 2) V transpose -> [bh][d][s]
  vtrans_kernel<<<dim3(16, 32), blk, 0, stream>>>(vh, vl, vth, vtl);

  // 3) flash attention -> attn_out hi/lo [token][E]
  attn_kernel<<<dim3(16, 32), blk, smemAttn, stream>>>(qh, ql, kh, kl, vth, vtl, aoh, aol);

  // 4) out_proj + bias + residual -> pre1
  gemm_kernel<1><<<dim3(8, 16, 1), blk, smemGemm, stream>>>(
      nullptr, aoh, aol, opw, opb, x, pre1, nullptr,
      nullptr, nullptr, nullptr, nullptr, nullptr, nullptr, nullptr, nullptr, 1024);

  // 5) LN1 -> l1f (f32) + l1b (bf16)
  ln_kernel<<<dim3(T_), blk, 0, stream>>>(pre1, ln1g, ln1b, l1f, l1b);

  // 6) gate + routing (padded 128-aligned slots)
  gate_kernel<<<dim3(T_ / 4), blk, 0, stream>>>(l1f, gw, gb, eid, cnt);
  scan_kernel<<<1, 64, 0, stream>>>(cnt, offs, offsp, cur);
  scatter_kernel<<<dim3(T_ / 256), blk, 0, stream>>>(eid, offsp, cur, perm, inv);

  // 7) expert FFN up: h = gelu(t @ w1^T + b1) -> hbuf (bf16, slot-major)
  gemm_kernel<2><<<dim3(32, 24, 1), blk, smemGemm, stream>>>(
      nullptr, l1b, nullptr, w1, b1, nullptr, nullptr, hbuf,
      nullptr, nullptr, nullptr, nullptr, nullptr, nullptr, offsp, perm, 1024);

  // 8) expert FFN down, split-K -> fp32 partials [kz][slot][E]
  gemm_kernel<3><<<dim3(8, 24, SPLITK_), blk, smemGemm, stream>>>(
      nullptr, hbuf, nullptr, w2, nullptr, nullptr, part, nullptr,
      nullptr, nullptr, nullptr, nullptr, nullptr, nullptr, offsp, perm, 1024);

  // 9) LN2 (fused split-K reduce + b2 + residual) -> d_out
  ln2_kernel<<<dim3(T_), blk, 0, stream>>>(part, l1f, b2, eid, inv, ln2g, ln2b, out);

  (void)in_sizes; (void)n_in; (void)out_size; (void)ws_size;
}

// Round 4
// 385.597 us; speedup vs baseline: 1.4273x; 1.0249x over previous
//
#include <hip/hip_runtime.h>
#include <hip/hip_bf16.h>
#include <math.h>

#define DI __device__ __forceinline__

typedef __bf16 bf16_t;
typedef bf16_t bf16x8 __attribute__((ext_vector_type(8)));
typedef bf16_t bf16x4 __attribute__((ext_vector_type(4)));
typedef float f32x4 __attribute__((ext_vector_type(4)));

constexpr int S_ = 1024, B_ = 2, E_ = 1024, H_ = 16, HD_ = 64;
constexpr int T_ = S_ * B_;      // 2048 tokens
constexpr int DFF_ = 4096, NE_ = 8;
constexpr int SLOTS_ = 3072;     // padded slot capacity
constexpr int SPLITK_ = 4;       // K-split for MoE down-proj

DI f32x4 mfma16(bf16x8 a, bf16x8 b, f32x4 c) {
  return __builtin_amdgcn_mfma_f32_16x16x32_bf16(a, b, c, 0, 0, 0);
}

// split fp32 into hi/lo bf16 (v ~= hi + lo, residual ~2^-18 relative)
DI void split2(float v, bf16_t& h, bf16_t& l) {
  h = (bf16_t)v;
  l = (bf16_t)(v - (float)h);
}

// ---------------------------------------------------------------------------
// 128x128-tile MFMA GEMM, double-buffered LDS + 2-deep register prefetch.
// XOR-swizzled unpadded LDS (row byte addr ^= (row&7)<<4).
// C[m,n] = sum_k A[m,k]*B[n,k]  (B row-major [N][K]).
// MODE 0: QKV     A=x fp32 (split),  epi: +bias, scale Q, scatter hi/lo QKV
// MODE 1: OUTPROJ A=attn hi/lo bf16 (split), epi: +bias +x residual -> f32
// MODE 2: MOE1    A=ln1 bf16 gathered via padded perm, epi: +b1, gelu -> bf16
// MODE 3: MOE2    A=hbuf bf16 slot-major, split-K over z, epi: fp32 partials
// ---------------------------------------------------------------------------
template <int MODE>
__launch_bounds__(256, 2)
__global__ void gemm_kernel(const float* Af32, const bf16_t* Abh, const bf16_t* Abl,
                            const float* Bw, const float* bias, const float* res,
                            float* Cf32, bf16_t* Cbf,
                            bf16_t* Qh, bf16_t* Ql, bf16_t* Kh2, bf16_t* Kl2,
                            bf16_t* Vh2, bf16_t* Vl2,
                            const int* offs_pad, const int* perm, int Kdim) {
  constexpr bool SPLIT = (MODE <= 1);
  constexpr int BK = SPLIT ? 32 : 64;
  constexpr int RB = BK * 2;           // row bytes (unpadded)
  constexpr int MATB = 128 * RB;       // one matrix tile, bytes
  constexpr int NMAT = SPLIT ? 4 : 2;  // Ah,Al,Bh,Bl | Ah,Bh
  constexpr int BUFB = NMAT * MATB;    // 32768; x2 buffers = 65536 total
  extern __shared__ char smem[];

  const int tid = threadIdx.x, lane = tid & 63, wv = tid >> 6;
  const int n0 = blockIdx.x * 128, m0 = blockIdx.y * 128;

  int e = 0;
  if constexpr (MODE >= 2) {
    if (m0 >= offs_pad[8]) return;  // uniform early exit, before any barrier
#pragma unroll
    for (int i = 1; i < 8; i++) e += (m0 >= offs_pad[i]);
  }
  const int kz = (MODE == 3) ? blockIdx.z : 0;

  const bf16_t* Abase = Abh;
  const float* Bp = Bw;
  size_t lda = (size_t)Kdim, ldb = (size_t)Kdim;
  if constexpr (MODE == 2) {
    Bp += (size_t)e * DFF_ * E_;
  } else if constexpr (MODE == 3) {
    Abase = Abh + (size_t)kz * 1024;
    Bp = Bw + (size_t)e * E_ * DFF_ + (size_t)kz * 1024;
    lda = DFF_;
    ldb = DFF_;
  }

  // hoisted A-row gather indices (MODE>=2)
  int asrc[4];
  if constexpr (MODE >= 2) {
#pragma unroll
    for (int i = 0; i < 4; i++) {
      int row = m0 + (tid >> 3) + i * 32;
      asrc[i] = (MODE == 2) ? perm[row] : row;
    }
  }

  // LDS byte-offset swizzle (store & read identical)
  auto SW = [&](int row, int cb) { return (row * RB + cb) ^ ((row & 7) << 4); };

  // two named staging register sets (static indexing only — no runtime idx)
  struct StageRegs {
    f32x4 ra[(MODE == 0) ? 4 : 1];
    bf16x8 rah[(MODE == 1) ? 2 : ((MODE == 0) ? 1 : 4)];
    bf16x8 ral[(MODE == 1) ? 2 : 1];
    f32x4 rb[SPLIT ? 4 : 8];
  } S0, S1;

  auto LOAD = [&](StageRegs& S, int k0) {
    if constexpr (MODE == 0) {
#pragma unroll
      for (int i = 0; i < 4; i++)
        S.ra[i] = *(const f32x4*)&Af32[(size_t)(m0 + (tid >> 3) + i * 32) * lda + k0 + (tid & 7) * 4];
    } else if constexpr (MODE == 1) {
#pragma unroll
      for (int i = 0; i < 2; i++) {
        size_t g = (size_t)(m0 + (tid >> 2) + i * 64) * lda + k0 + (tid & 3) * 8;
        S.rah[i] = *(const bf16x8*)&Abh[g];
        S.ral[i] = *(const bf16x8*)&Abl[g];
      }
    } else {
#pragma unroll
      for (int i = 0; i < 4; i++)
        S.rah[i] = *(const bf16x8*)&Abase[(size_t)asrc[i] * lda + k0 + (tid & 7) * 8];
    }
    if constexpr (SPLIT) {
#pragma unroll
      for (int i = 0; i < 4; i++)
        S.rb[i] = *(const f32x4*)&Bp[(size_t)(n0 + (tid >> 3) + i * 32) * ldb + k0 + (tid & 7) * 4];
    } else {
#pragma unroll
      for (int i = 0; i < 8; i++)
        S.rb[i] = *(const f32x4*)&Bp[(size_t)(n0 + (tid >> 4) + i * 16) * ldb + k0 + (tid & 15) * 4];
    }
  };

  auto STORE = [&](StageRegs& S, char* base) {
    char* Ahb = base;
    char* Alb = base + (SPLIT ? MATB : 0);
    char* Bhb = base + (SPLIT ? 2 : 1) * MATB;
    char* Blb = Bhb + (SPLIT ? MATB : 0);
    if constexpr (MODE == 0) {
#pragma unroll
      for (int i = 0; i < 4; i++) {
        int row = (tid >> 3) + i * 32, cb = (tid & 7) * 8;
        bf16x4 hv, lv;
#pragma unroll
        for (int j = 0; j < 4; j++) { bf16_t h, l; split2(S.ra[i][j], h, l); hv[j] = h; lv[j] = l; }
        *(bf16x4*)(Ahb + SW(row, cb)) = hv;
        *(bf16x4*)(Alb + SW(row, cb)) = lv;
      }
    } else if constexpr (MODE == 1) {
#pragma unroll
      for (int i = 0; i < 2; i++) {
        int row = (tid >> 2) + i * 64, cb = (tid & 3) * 16;
        *(bf16x8*)(Ahb + SW(row, cb)) = S.rah[i];
        *(bf16x8*)(Alb + SW(row, cb)) = S.ral[i];
      }
    } else {
#pragma unroll
      for (int i = 0; i < 4; i++) {
        int row = (tid >> 3) + i * 32, cb = (tid & 7) * 16;
        *(bf16x8*)(Ahb + SW(row, cb)) = S.rah[i];
      }
    }
    if constexpr (SPLIT) {
#pragma unroll
      for (int i = 0; i < 4; i++) {
        int row = (tid >> 3) + i * 32, cb = (tid & 7) * 8;
        bf16x4 hv, lv;
#pragma unroll
        for (int j = 0; j < 4; j++) { bf16_t h, l; split2(S.rb[i][j], h, l); hv[j] = h; lv[j] = l; }
        *(bf16x4*)(Bhb + SW(row, cb)) = hv;
        *(bf16x4*)(Blb + SW(row, cb)) = lv;
      }
    } else {
#pragma unroll
      for (int i = 0; i < 8; i++) {
        int row = (tid >> 4) + i * 16, cb = (tid & 15) * 8;
        bf16x4 hv;
#pragma unroll
        for (int j = 0; j < 4; j++) hv[j] = (bf16_t)S.rb[i][j];
        *(bf16x4*)(Bhb + SW(row, cb)) = hv;
      }
    }
  };

  f32x4 acc[4][4];
#pragma unroll
  for (int i = 0; i < 4; i++)
#pragma unroll
    for (int j = 0; j < 4; j++) acc[i][j] = (f32x4){0.f, 0.f, 0.f, 0.f};

  const int wm = (wv >> 1) * 64, wn = (wv & 1) * 64;
  const int lr = lane & 15, lk = (lane >> 4) * 8;

  auto COMPUTE = [&](const char* base) {
    const char* Ahb = base;
    const char* Alb = base + (SPLIT ? MATB : 0);
    const char* Bhb = base + (SPLIT ? 2 : 1) * MATB;
    const char* Blb = Bhb + (SPLIT ? MATB : 0);
#pragma unroll
    for (int kk = 0; kk < BK / 32; ++kk) {
      const int cb = (kk * 32 + lk) * 2;
      bf16x8 afh[4], afl[4];
#pragma unroll
      for (int fm = 0; fm < 4; fm++) {
        afh[fm] = *(const bf16x8*)(Ahb + SW(wm + fm * 16 + lr, cb));
        if constexpr (SPLIT)
          afl[fm] = *(const bf16x8*)(Alb + SW(wm + fm * 16 + lr, cb));
      }
#pragma unroll
      for (int fn = 0; fn < 4; fn++) {
        bf16x8 bfh = *(const bf16x8*)(Bhb + SW(wn + fn * 16 + lr, cb));
        bf16x8 bfl;
        if constexpr (SPLIT)
          bfl = *(const bf16x8*)(Blb + SW(wn + fn * 16 + lr, cb));
#pragma unroll
        for (int fm = 0; fm < 4; fm++) {
          acc[fm][fn] = mfma16(afh[fm], bfh, acc[fm][fn]);
          if constexpr (SPLIT) {
            acc[fm][fn] = mfma16(afh[fm], bfl, acc[fm][fn]);
            acc[fm][fn] = mfma16(afl[fm], bfh, acc[fm][fn]);
          }
        }
      }
    }
  };

  // ---- 3-stage pipeline: load(k+2) | compute(k) | store(k+1), all static ----
  const int nK = Kdim / BK;   // >= 16 always
  LOAD(S0, 0);
  LOAD(S1, BK);
  STORE(S0, smem);
  __syncthreads();
  int kt = 0;
  while (true) {
    if (kt + 2 < nK) LOAD(S0, (kt + 2) * BK);
    COMPUTE(smem);
    if (kt + 1 >= nK) break;
    STORE(S1, smem + BUFB);
    __syncthreads();
    ++kt;
    if (kt + 2 < nK) LOAD(S1, (kt + 2) * BK);
    COMPUTE(smem + BUFB);
    if (kt + 1 >= nK) break;
    STORE(S0, smem);
    __syncthreads();
    ++kt;
  }

  // ---- epilogue.  C/D layout: col = lane&15, row = (lane>>4)*4 + reg ----
  const int lr4 = (lane >> 4) * 4;
#pragma unroll
  for (int fm = 0; fm < 4; fm++) {
#pragma unroll
    for (int fn = 0; fn < 4; fn++) {
#pragma unroll
      for (int r = 0; r < 4; r++) {
        float v = acc[fm][fn][r];
        int row = wm + fm * 16 + lr4 + r;
        int col = wn + fn * 16 + lr;
        if constexpr (MODE == 0) {
          int gm = m0 + row, gn = n0 + col;
          v += bias[gn];
          int sec = gn >> 10, ee = gn & 1023, hh = ee >> 6, dd = ee & 63;
          if (sec == 0) v *= 0.125f;  // 1/sqrt(64), applied after bias like ref
          int ss = gm >> 1, bb = gm & 1, bhp = bb * 16 + hh;
          size_t di = ((size_t)bhp * 1024 + ss) * 64 + dd;
          bf16_t oh, ol; split2(v, oh, ol);
          bf16_t* dh = (sec == 0) ? Qh : (sec == 1) ? Kh2 : Vh2;
          bf16_t* dl = (sec == 0) ? Ql : (sec == 1) ? Kl2 : Vl2;
          dh[di] = oh; dl[di] = ol;
        } else if constexpr (MODE == 1) {
          int gm = m0 + row, gn = n0 + col;
          v += bias[gn] + res[(size_t)gm * E_ + gn];
          Cf32[(size_t)gm * E_ + gn] = v;
        } else if constexpr (MODE == 2) {
          int slot = m0 + row, gn = n0 + col;
          v += bias[e * DFF_ + gn];
          v = 0.5f * v * (1.0f + erff(v * 0.70710678118654752440f));  // exact gelu
          Cbf[(size_t)slot * DFF_ + gn] = (bf16_t)v;
        } else {
          int slot = m0 + row, gn = n0 + col;
          Cf32[((size_t)kz * SLOTS_ + slot) * E_ + gn] = v;
        }
      }
    }
  }
}

// ---------------------------------------------------------------------------
// V transpose: [bh][s][d] -> [bh][d][s] (hi and lo), LDS-tiled, coalesced.
// ---------------------------------------------------------------------------
__launch_bounds__(256)
__global__ void vtrans_kernel(const bf16_t* vh, const bf16_t* vl,
                              bf16_t* vth, bf16_t* vtl) {
  const int bh = blockIdx.y, s0 = blockIdx.x * 64;
  const int tid = threadIdx.x;
  __shared__ bf16_t th[64][72];
  __shared__ bf16_t tl[64][72];
#pragma unroll
  for (int i = 0; i < 2; i++) {
    int f = tid + i * 256, r = f >> 3, c = (f & 7) * 8;
    size_t g = ((size_t)bh * 1024 + s0 + r) * 64 + c;
    *(bf16x8*)&th[r][c] = *(const bf16x8*)&vh[g];
    *(bf16x8*)&tl[r][c] = *(const bf16x8*)&vl[g];
  }
  __syncthreads();
#pragma unroll
  for (int i = 0; i < 2; i++) {
    int f = tid + i * 256, d = f >> 3, c2 = (f & 7) * 8;
    bf16x8 oh, ol;
#pragma unroll
    for (int j = 0; j < 8; j++) { oh[j] = th[c2 + j][d]; ol[j] = tl[c2 + j][d]; }
    size_t g = ((size_t)bh * 64 + d) * 1024 + s0 + c2;
    *(bf16x8*)&vth[g] = oh;
    *(bf16x8*)&vtl[g] = ol;
  }
}

// ---------------------------------------------------------------------------
// Flash attention, split-bf16.  Block = (q-tile of 64 rows) x (one bh).
// ---------------------------------------------------------------------------
__launch_bounds__(256)
__global__ void attn_kernel(const bf16_t* gqh, const bf16_t* gql,
                            const bf16_t* gkh, const bf16_t* gkl,
                            const bf16_t* gvth, const bf16_t* gvtl,
                            bf16_t* aoh, bf16_t* aol) {
  const int bh = blockIdx.y, q0 = blockIdx.x * 64;
  const int tid = threadIdx.x, lane = tid & 63, wv = tid >> 6;
  const int lr = lane & 15, lk = (lane >> 4) * 8, lr4 = (lane >> 4) * 4;
  extern __shared__ char smem[];
  bf16_t* Kh = (bf16_t*)smem;       // [64][72]
  bf16_t* Kl = Kh + 64 * 72;
  bf16_t* Vh = Kl + 64 * 72;        // transposed [d][t]
  bf16_t* Vl = Vh + 64 * 72;
  bf16_t* Ph = Vl + 64 * 72;        // [64][72]
  bf16_t* Pl = Ph + 64 * 72;

  const size_t qbase = ((size_t)bh * 1024 + q0 + wv * 16 + lr) * 64;
  bf16x8 qfh[2], qfl[2];
  qfh[0] = *(const bf16x8*)&gqh[qbase + lk];
  qfh[1] = *(const bf16x8*)&gqh[qbase + 32 + lk];
  qfl[0] = *(const bf16x8*)&gql[qbase + lk];
  qfl[1] = *(const bf16x8*)&gql[qbase + 32 + lk];

  f32x4 oacc[4];
#pragma unroll
  for (int i = 0; i < 4; i++) oacc[i] = (f32x4){0.f, 0.f, 0.f, 0.f};
  float m_r[4], l_r[4];
#pragma unroll
  for (int r = 0; r < 4; r++) { m_r[r] = -INFINITY; l_r[r] = 0.f; }

  for (int t0 = 0; t0 < S_; t0 += 64) {
    __syncthreads();
#pragma unroll
    for (int i = 0; i < 2; i++) {
      int f = tid + i * 256, r = f >> 3, c = (f & 7) * 8;
      size_t gk = ((size_t)bh * 1024 + t0 + r) * 64 + c;
      *(bf16x8*)&Kh[r * 72 + c] = *(const bf16x8*)&gkh[gk];
      *(bf16x8*)&Kl[r * 72 + c] = *(const bf16x8*)&gkl[gk];
      size_t gv = ((size_t)bh * 64 + r) * 1024 + t0 + c;
      *(bf16x8*)&Vh[r * 72 + c] = *(const bf16x8*)&gvth[gv];
      *(bf16x8*)&Vl[r * 72 + c] = *(const bf16x8*)&gvtl[gv];
    }
    __syncthreads();
    f32x4 sacc[4];
#pragma unroll
    for (int i = 0; i < 4; i++) sacc[i] = (f32x4){0.f, 0.f, 0.f, 0.f};
#pragma unroll
    for (int kk = 0; kk < 2; ++kk) {
#pragma unroll
      for (int fn = 0; fn < 4; ++fn) {
        bf16x8 kbh = *(const bf16x8*)&Kh[(fn * 16 + lr) * 72 + kk * 32 + lk];
        bf16x8 kbl = *(const bf16x8*)&Kl[(fn * 16 + lr) * 72 + kk * 32 + lk];
        sacc[fn] = mfma16(qfh[kk], kbh, sacc[fn]);
        sacc[fn] = mfma16(qfh[kk], kbl, sacc[fn]);
        sacc[fn] = mfma16(qfl[kk], kbh, sacc[fn]);
      }
    }
#pragma unroll
    for (int r = 0; r < 4; r++) {
      float mx = fmaxf(fmaxf(sacc[0][r], sacc[1][r]), fmaxf(sacc[2][r], sacc[3][r]));
#pragma unroll
      for (int off = 1; off < 16; off <<= 1) mx = fmaxf(mx, __shfl_xor(mx, off));
      float mn = fmaxf(m_r[r], mx);
      float al = expf(m_r[r] - mn);
      l_r[r] *= al;
#pragma unroll
      for (int fd = 0; fd < 4; fd++) oacc[fd][r] *= al;
      float ps = 0.f;
      int pr = wv * 16 + lr4 + r;
#pragma unroll
      for (int fn = 0; fn < 4; fn++) {
        float p = expf(sacc[fn][r] - mn);
        ps += p;
        bf16_t ph, pl; split2(p, ph, pl);
        Ph[pr * 72 + fn * 16 + lr] = ph;
        Pl[pr * 72 + fn * 16 + lr] = pl;
      }
#pragma unroll
      for (int off = 1; off < 16; off <<= 1) ps += __shfl_xor(ps, off);
      l_r[r] += ps;
      m_r[r] = mn;
    }
    __syncthreads();
#pragma unroll
    for (int kk = 0; kk < 2; kk++) {
      bf16x8 pah = *(const bf16x8*)&Ph[(wv * 16 + lr) * 72 + kk * 32 + lk];
      bf16x8 pal = *(const bf16x8*)&Pl[(wv * 16 + lr) * 72 + kk * 32 + lk];
#pragma unroll
      for (int fd = 0; fd < 4; fd++) {
        bf16x8 vbh = *(const bf16x8*)&Vh[(fd * 16 + lr) * 72 + kk * 32 + lk];
        bf16x8 vbl = *(const bf16x8*)&Vl[(fd * 16 + lr) * 72 + kk * 32 + lk];
        oacc[fd] = mfma16(pah, vbh, oacc[fd]);
        oacc[fd] = mfma16(pah, vbl, oacc[fd]);
        oacc[fd] = mfma16(pal, vbh, oacc[fd]);
      }
    }
  }
  const int b = bh >> 4, h = bh & 15;
#pragma unroll
  for (int fd = 0; fd < 4; fd++) {
#pragma unroll
    for (int r = 0; r < 4; r++) {
      float v = oacc[fd][r] / l_r[r];
      int s = q0 + wv * 16 + lr4 + r;
      int d = fd * 16 + lr;
      size_t idx = ((size_t)(s * 2 + b)) * 1024 + h * 64 + d;
      bf16_t oh, ol; split2(v, oh, ol);
      aoh[idx] = oh;
      aol[idx] = ol;
    }
  }
}

// ---------------------------------------------------------------------------
// LN1: row LayerNorm over E=1024, writes f32 + bf16.
// ---------------------------------------------------------------------------
__launch_bounds__(256)
__global__ void ln_kernel(const float* in, const float* g, const float* bt,
                          float* outf, bf16_t* outb) {
  const int row = blockIdx.x, tid = threadIdx.x;
  f32x4 v = *(const f32x4*)&in[(size_t)row * 1024 + tid * 4];
  float s = v[0] + v[1] + v[2] + v[3];
  float q = v[0] * v[0] + v[1] * v[1] + v[2] * v[2] + v[3] * v[3];
#pragma unroll
  for (int off = 1; off < 64; off <<= 1) { s += __shfl_xor(s, off); q += __shfl_xor(q, off); }
  __shared__ float ss[4], qq[4];
  int wv = tid >> 6;
  if ((tid & 63) == 0) { ss[wv] = s; qq[wv] = q; }
  __syncthreads();
  s = ss[0] + ss[1] + ss[2] + ss[3];
  q = qq[0] + qq[1] + qq[2] + qq[3];
  float mu = s * (1.f / 1024.f);
  float var = q * (1.f / 1024.f) - mu * mu;
  float rs = rsqrtf(var + 1e-5f);
  f32x4 gg = *(const f32x4*)&g[tid * 4];
  f32x4 bb = *(const f32x4*)&bt[tid * 4];
  f32x4 o;
#pragma unroll
  for (int j = 0; j < 4; j++) o[j] = (v[j] - mu) * rs * gg[j] + bb[j];
  *(f32x4*)&outf[(size_t)row * 1024 + tid * 4] = o;
  bf16x4 ob;
#pragma unroll
  for (int j = 0; j < 4; j++) ob[j] = (bf16_t)o[j];
  *(bf16x4*)&outb[(size_t)row * 1024 + tid * 4] = ob;
}

// ---------------------------------------------------------------------------
// LN2 fused with split-K reduce + b2 + residual.
// ---------------------------------------------------------------------------
__launch_bounds__(256)
__global__ void ln2_kernel(const float* part, const float* l1f, const float* b2,
                           const int* eid, const int* inv, const float* g,
                           const float* bt, float* out) {
  const int t = blockIdx.x, tid = threadIdx.x;
  const int st = inv[t], e = eid[t];
  const int j = tid * 4;
  f32x4 v = *(const f32x4*)&part[(size_t)st * 1024 + j];
#pragma unroll
  for (int kz = 1; kz < SPLITK_; kz++) {
    f32x4 p = *(const f32x4*)&part[((size_t)kz * SLOTS_ + st) * 1024 + j];
#pragma unroll
    for (int i = 0; i < 4; i++) v[i] += p[i];
  }
  f32x4 bb2 = *(const f32x4*)&b2[e * 1024 + j];
  f32x4 rr = *(const f32x4*)&l1f[(size_t)t * 1024 + j];
#pragma unroll
  for (int i = 0; i < 4; i++) v[i] += bb2[i] + rr[i];

  float s = v[0] + v[1] + v[2] + v[3];
  float q = v[0] * v[0] + v[1] * v[1] + v[2] * v[2] + v[3] * v[3];
#pragma unroll
  for (int off = 1; off < 64; off <<= 1) { s += __shfl_xor(s, off); q += __shfl_xor(q, off); }
  __shared__ float ss[4], qq[4];
  int wv = tid >> 6;
  if ((tid & 63) == 0) { ss[wv] = s; qq[wv] = q; }
  __syncthreads();
  s = ss[0] + ss[1] + ss[2] + ss[3];
  q = qq[0] + qq[1] + qq[2] + qq[3];
  float mu = s * (1.f / 1024.f);
  float var = q * (1.f / 1024.f) - mu * mu;
  float rs = rsqrtf(var + 1e-5f);
  f32x4 gg = *(const f32x4*)&g[tid * 4];
  f32x4 bb = *(const f32x4*)&bt[tid * 4];
  f32x4 o;
#pragma unroll
  for (int jj = 0; jj < 4; jj++) o[jj] = (v[jj] - mu) * rs * gg[jj] + bb[jj];
  *(f32x4*)&out[(size_t)t * 1024 + j] = o;
}

// ---------------------------------------------------------------------------
// Gate: fp32 logits, argmax (first max), per-expert counts.
// ---------------------------------------------------------------------------
__launch_bounds__(256)
__global__ void gate_kernel(const float* ln1f, const float* gw, const float* gb,
                            int* eid, int* cnt) {
  const int t = blockIdx.x * 4 + (threadIdx.x >> 6);
  const int lane = threadIdx.x & 63;
  float a[8] = {0, 0, 0, 0, 0, 0, 0, 0};
  for (int k0 = lane * 4; k0 < 1024; k0 += 256) {
    f32x4 xv = *(const f32x4*)&ln1f[(size_t)t * 1024 + k0];
#pragma unroll
    for (int ee = 0; ee < 8; ee++) {
      f32x4 wv4 = *(const f32x4*)&gw[ee * 1024 + k0];
      a[ee] += xv[0] * wv4[0] + xv[1] * wv4[1] + xv[2] * wv4[2] + xv[3] * wv4[3];
    }
  }
#pragma unroll
  for (int ee = 0; ee < 8; ee++)
#pragma unroll
    for (int off = 1; off < 64; off <<= 1) a[ee] += __shfl_xor(a[ee], off);
  if (lane == 0) {
    float best = a[0] + gb[0];
    int be = 0;
#pragma unroll
    for (int ee = 1; ee < 8; ee++) {
      float vv = a[ee] + gb[ee];
      if (vv > best) { best = vv; be = ee; }
    }
    eid[t] = be;
    atomicAdd(&cnt[be], 1);
  }
}

__global__ void zero_kernel(int* cnt) {
  if (threadIdx.x < 8) cnt[threadIdx.x] = 0;
}

__global__ void scan_kernel(const int* cnt, int* offs, int* offs_pad, int* cur) {
  if (threadIdx.x == 0) {
    int o = 0, op = 0;
    for (int e = 0; e < 8; e++) {
      offs[e] = o; offs_pad[e] = op;
      o += cnt[e]; op += (cnt[e] + 127) & ~127;
      cur[e] = 0;
    }
    offs[8] = o; offs_pad[8] = op;
  }
}

__global__ void scatter_kernel(const int* eid, const int* offs_pad, int* cur,
                               int* perm, int* inv) {
  int t = blockIdx.x * 256 + threadIdx.x;
  int ee = eid[t];
  int pos = atomicAdd(&cur[ee], 1);
  int slot = offs_pad[ee] + pos;
  perm[slot] = t;
  inv[t] = slot;
}

// ---------------------------------------------------------------------------
extern "C" void kernel_launch(void* const* d_in, const int* in_sizes, int n_in,
                              void* d_out, int out_size, void* d_ws, size_t ws_size,
                              hipStream_t stream) {
  const float* x    = (const float*)d_in[0];
  const float* ipw  = (const float*)d_in[1];
  const float* ipb  = (const float*)d_in[2];
  const float* opw  = (const float*)d_in[3];
  const float* opb  = (const float*)d_in[4];
  const float* ln1g = (const float*)d_in[5];
  const float* ln1b = (const float*)d_in[6];
  const float* ln2g = (const float*)d_in[7];
  const float* ln2b = (const float*)d_in[8];
  const float* gw   = (const float*)d_in[9];
  const float* gb   = (const float*)d_in[10];
  const float* w1   = (const float*)d_in[11];
  const float* b1   = (const float*)d_in[12];
  const float* w2   = (const float*)d_in[13];
  const float* b2   = (const float*)d_in[14];
  float* out = (float*)d_out;

  char* w = (char*)d_ws;
  auto alloc = [&](size_t n) { char* p = w; w += (n + 255) & ~(size_t)255; return p; };
  const size_t NBH = (size_t)32 * 1024 * 64;

  bf16_t* qh  = (bf16_t*)alloc(NBH * 2);
  bf16_t* ql  = (bf16_t*)alloc(NBH * 2);
  bf16_t* kh  = (bf16_t*)alloc(NBH * 2);
  bf16_t* kl  = (bf16_t*)alloc(NBH * 2);
  bf16_t* vh  = (bf16_t*)alloc(NBH * 2);
  bf16_t* vl  = (bf16_t*)alloc(NBH * 2);
  bf16_t* vth = (bf16_t*)alloc(NBH * 2);
  bf16_t* vtl = (bf16_t*)alloc(NBH * 2);
  bf16_t* aoh = (bf16_t*)alloc((size_t)T_ * E_ * 2);
  bf16_t* aol = (bf16_t*)alloc((size_t)T_ * E_ * 2);
  float*  pre1 = (float*)alloc((size_t)T_ * E_ * 4);
  bf16_t* l1b  = (bf16_t*)alloc((size_t)T_ * E_ * 2);
  float*  l1f  = (float*)alloc((size_t)T_ * E_ * 4);
  bf16_t* hbuf = (bf16_t*)alloc((size_t)SLOTS_ * DFF_ * 2);
  float*  part = (float*)alloc((size_t)SPLITK_ * SLOTS_ * E_ * 4);
  int* eid  = (int*)alloc(T_ * 4);
  int* cnt  = (int*)alloc(16 * 4);
  int* offs = (int*)alloc(16 * 4);
  int* offsp = (int*)alloc(16 * 4);
  int* cur  = (int*)alloc(16 * 4);
  int* perm = (int*)alloc(SLOTS_ * 4);
  int* inv  = (int*)alloc(T_ * 4);

  const dim3 blk(256);
  const int smemGemm = 65536;           // 2 x 32768-byte double buffers
  const int smemAttn = 6 * 64 * 72 * 2; // 55296

  zero_kernel<<<1, 64, 0, stream>>>(cnt);
  hipMemsetAsync(perm, 0, SLOTS_ * 4, stream);  // padded perm entries -> token 0

  // 1) QKV projection (split) -> Q/K/V hi/lo in [bh][s][d]
  gemm_kernel<0><<<dim3(24, 16, 1), blk, smemGemm, stream>>>(
      x, nullptr, nullptr, ipw, ipb, nullptr, nullptr, nullptr,
      qh, ql, kh, kl, vh, vl, nullptr, nullptr, 1024);

  // 2) V transpose -> [bh][d][s]
  vtrans_kernel<<<dim3(16, 32), blk, 0, stream>>>(vh, vl, vth, vtl);

  // 3) flash attention -> attn_out hi/lo [token][E]
  attn_kernel<<<dim3(16, 32), blk, smemAttn, stream>>>(qh, ql, kh, kl, vth, vtl, aoh, aol);

  // 4) out_proj + bias + residual -> pre1
  gemm_kernel<1><<<dim3(8, 16, 1), blk, smemGemm, stream>>>(
      nullptr, aoh, aol, opw, opb, x, pre1, nullptr,
      nullptr, nullptr, nullptr, nullptr, nullptr, nullptr, nullptr, nullptr, 1024);

  // 5) LN1 -> l1f (f32) + l1b (bf16)
  ln_kernel<<<dim3(T_), blk, 0, stream>>>(pre1, ln1g, ln1b, l1f, l1b);

  // 6) gate + routing (padded 128-aligned slots)
  gate_kernel<<<dim3(T_ / 4), blk, 0, stream>>>(l1f, gw, gb, eid, cnt);
  scan_kernel<<<1, 64, 0, stream>>>(cnt, offs, offsp, cur);
  scatter_kernel<<<dim3(T_ / 256), blk, 0, stream>>>(eid, offsp, cur, perm, inv);

  // 7) expert FFN up: h = gelu(t @ w1^T + b1) -> hbuf (bf16, slot-major)
  gemm_kernel<2><<<dim3(32, 24, 1), blk, smemGemm, stream>>>(
      nullptr, l1b, nullptr, w1, b1, nullptr, nullptr, hbuf,
      nullptr, nullptr, nullptr, nullptr, nullptr, nullptr, offsp, perm, 1024);

  // 8) expert FFN down, split-K -> fp32 partials [kz][slot][E]
  gemm_kernel<3><<<dim3(8, 24, SPLITK_), blk, smemGemm, stream>>>(
      nullptr, hbuf, nullptr, w2, nullptr, nullptr, part, nullptr,
      nullptr, nullptr, nullptr, nullptr, nullptr, nullptr, offsp, perm, 1024);

  // 9) LN2 (fused split-K reduce + b2 + residual) -> d_out
  ln2_kernel<<<dim3(T_), blk, 0, stream>>>(part, l1f, b2, eid, inv, ln2g, ln2b, out);

  (void)in_sizes; (void)n_in; (void)out_size; (void)ws_size;
}

// Round 5
// 380.072 us; speedup vs baseline: 1.4480x; 1.0145x over previous
//
#include <hip/hip_runtime.h>
#include <hip/hip_bf16.h>
#include <math.h>

#define DI __device__ __forceinline__

typedef __bf16 bf16_t;
typedef bf16_t bf16x8 __attribute__((ext_vector_type(8)));
typedef bf16_t bf16x4 __attribute__((ext_vector_type(4)));
typedef float f32x4 __attribute__((ext_vector_type(4)));

constexpr int S_ = 1024, B_ = 2, E_ = 1024, H_ = 16, HD_ = 64;
constexpr int T_ = S_ * B_;      // 2048 tokens
constexpr int DFF_ = 4096, NE_ = 8;
constexpr int SLOTS_ = 3072;     // padded slot capacity
constexpr int SPLITK_ = 4;       // K-split for MoE down-proj

DI f32x4 mfma16(bf16x8 a, bf16x8 b, f32x4 c) {
  return __builtin_amdgcn_mfma_f32_16x16x32_bf16(a, b, c, 0, 0, 0);
}

DI void split2(float v, bf16_t& h, bf16_t& l) {
  h = (bf16_t)v;
  l = (bf16_t)(v - (float)h);
}

// direct global->LDS async copy, 16B per lane (lane i -> ldsbase + i*16)
typedef const __attribute__((address_space(1))) void* gas_p;
typedef __attribute__((address_space(3))) void* las_p;
DI void gll16(const void* g, void* l) {
  __builtin_amdgcn_global_load_lds((gas_p)g, (las_p)l, 16, 0, 0);
}

// Universal swizzle: within each 128B row-chunk, 16B-unit u lives at slot
// u ^ (row&7).  Pre-swizzled global buffers are copied LINEARLY into LDS by
// global_load_lds; all LDS readers apply the same XOR.
DI int swslot(int u, int r) { return u ^ (r & 7); }

// ---------------------------------------------------------------------------
// Prep kernels: fp32 weights -> bf16 pre-swizzled chunk layouts.
// Non-split: chunk = 64 elems = 8 units (hi only).  NCH = K/64 (compile-time).
// ---------------------------------------------------------------------------
template <int NCH, int LOG2NCH>
__launch_bounds__(256)
__global__ void prep_w(const float* src, bf16_t* dst) {
  int f = blockIdx.x * 256 + threadIdx.x;
  int u = f & 7, chunk = (f >> 3) & (NCH - 1), row = f >> (3 + LOG2NCH);
  const float* s = src + (size_t)row * (NCH * 64) + chunk * 64 + u * 8;
  f32x4 a = *(const f32x4*)s, b = *(const f32x4*)(s + 4);
  bf16x8 o;
#pragma unroll
  for (int j = 0; j < 4; j++) { o[j] = (bf16_t)a[j]; o[4 + j] = (bf16_t)b[j]; }
  char* d = (char*)dst + (size_t)row * (NCH * 128) + chunk * 128 + swslot(u, row) * 16;
  *(bf16x8*)d = o;
}

// Split: chunk = 32 elems = {hi 4 units | lo 4 units}.  K = 1024 (32 chunks).
__launch_bounds__(256)
__global__ void prep_wsplit(const float* src, bf16_t* dst) {
  int f = blockIdx.x * 256 + threadIdx.x;
  int u = f & 3, chunk = (f >> 2) & 31, row = f >> 7;
  const float* s = src + (size_t)row * 1024 + chunk * 32 + u * 8;
  f32x4 a = *(const f32x4*)s, b = *(const f32x4*)(s + 4);
  bf16x8 hv, lv;
#pragma unroll
  for (int j = 0; j < 4; j++) {
    bf16_t h, l; split2(a[j], h, l); hv[j] = h; lv[j] = l;
    split2(b[j], h, l); hv[4 + j] = h; lv[4 + j] = l;
  }
  char* base = (char*)dst + (size_t)row * 4096 + chunk * 128;
  *(bf16x8*)(base + swslot(u, row) * 16) = hv;
  *(bf16x8*)(base + swslot(u + 4, row) * 16) = lv;
}

// gather LN1 rows into slot-major pre-swizzled bf16 (MOE1 A)
__launch_bounds__(256)
__global__ void gather_kernel(const float* l1f, const int* perm, bf16_t* l1g) {
  int f = blockIdx.x * 256 + threadIdx.x;
  int u = f & 7, chunk = (f >> 3) & 15, slot = f >> 7;
  int tok = perm[slot];
  const float* s = l1f + (size_t)tok * 1024 + chunk * 64 + u * 8;
  f32x4 a = *(const f32x4*)s, b = *(const f32x4*)(s + 4);
  bf16x8 o;
#pragma unroll
  for (int j = 0; j < 4; j++) { o[j] = (bf16_t)a[j]; o[4 + j] = (bf16_t)b[j]; }
  char* d = (char*)l1g + (size_t)slot * 2048 + chunk * 128 + swslot(u, slot) * 16;
  *(bf16x8*)d = o;
}

// ---------------------------------------------------------------------------
// Uniform 128x128 MFMA GEMM: A,B staged via global_load_lds from pre-swizzled
// bf16 buffers.  Per K-step: one 128B chunk per row; 8 gll instrs; 1 barrier.
// SPLIT modes (0,1): chunk = {hi32|lo32}, 48 MFMA/step.  Else 64 elems, 32.
// MODE 0: QKV   out: +bias, scale Q, scatter Q plain / K,V swizzled (hi/lo)
// MODE 1: OUTPROJ (split-K z=2) -> fp32 partials (bias/res deferred to LN1)
// MODE 2: MOE1  out: +b1, gelu -> hbuf bf16 swizzled
// MODE 3: MOE2  (split-K z=4) -> bf16 partials
// ---------------------------------------------------------------------------
template <int MODE>
__launch_bounds__(256, 2)
__global__ void gemm_kernel(const bf16_t* Ap, const bf16_t* Bp0,
                            const float* bias,
                            float* Cf, bf16_t* Cb,
                            bf16_t* Qh, bf16_t* Ql, bf16_t* Kh2, bf16_t* Kl2,
                            bf16_t* Vh2, bf16_t* Vl2,
                            const int* offs_pad) {
  constexpr bool SPLIT = (MODE <= 1);
  constexpr int NK = (MODE == 0) ? 32 : 16;
  constexpr int ARB = (MODE == 2) ? 2048 : ((MODE == 3) ? 8192 : 4096);
  constexpr int BRB = ARB;
  constexpr int BUFB = 32768;  // A tile 16KB + B tile 16KB
  extern __shared__ char smem[];

  const int tid = threadIdx.x, lane = tid & 63, wv = tid >> 6;
  const int n0 = blockIdx.x * 128, m0 = blockIdx.y * 128;

  int e = 0;
  if constexpr (MODE >= 2) {
    if (m0 >= offs_pad[8]) return;  // uniform early exit before any barrier
#pragma unroll
    for (int i = 1; i < 8; i++) e += (m0 >= offs_pad[i]);
  }
  const int kz = (MODE == 1 || MODE == 3) ? blockIdx.z : 0;
  const int ck0 = (MODE == 1 || MODE == 3) ? kz * 16 : 0;

  const char* Ab = (const char*)Ap;
  const char* Bb = (const char*)Bp0;
  if constexpr (MODE == 2) Bb += (size_t)e * 4096 * 2048;
  if constexpr (MODE == 3) Bb += (size_t)e * 1024 * 8192;

  auto STAGE = [&](char* lb, int ck) {
#pragma unroll
    for (int i = 0; i < 4; i++) {
      int f = i * 256 + tid, row = f >> 3, cb = (f & 7) * 16;
      gll16(Ab + (size_t)(m0 + row) * ARB + ck * 128 + cb, lb + f * 16);
    }
#pragma unroll
    for (int i = 0; i < 4; i++) {
      int f = i * 256 + tid, row = f >> 3, cb = (f & 7) * 16;
      gll16(Bb + (size_t)(n0 + row) * BRB + ck * 128 + cb, lb + 16384 + f * 16);
    }
  };

  f32x4 acc[4][4];
#pragma unroll
  for (int i = 0; i < 4; i++)
#pragma unroll
    for (int j = 0; j < 4; j++) acc[i][j] = (f32x4){0.f, 0.f, 0.f, 0.f};

  const int wm = (wv >> 1) * 64, wn = (wv & 1) * 64;
  const int lr = lane & 15;

  auto LB = [&](const char* base, int r, int u) {
    return *(const bf16x8*)(base + r * 128 + (swslot(u, r) << 4));
  };
  auto COMPUTE = [&](const char* lb) {
    const char* Abase = lb;
    const char* Bbase = lb + 16384;
    if constexpr (SPLIT) {
      const int u = lane >> 4;
      bf16x8 afh[4], afl[4];
#pragma unroll
      for (int fm = 0; fm < 4; fm++) {
        int r = wm + fm * 16 + lr;
        afh[fm] = LB(Abase, r, u);
        afl[fm] = LB(Abase, r, u + 4);
      }
#pragma unroll
      for (int fn = 0; fn < 4; fn++) {
        int r = wn + fn * 16 + lr;
        bf16x8 bfh = LB(Bbase, r, u);
        bf16x8 bfl = LB(Bbase, r, u + 4);
#pragma unroll
        for (int fm = 0; fm < 4; fm++) {
          acc[fm][fn] = mfma16(afh[fm], bfh, acc[fm][fn]);
          acc[fm][fn] = mfma16(afh[fm], bfl, acc[fm][fn]);
          acc[fm][fn] = mfma16(afl[fm], bfh, acc[fm][fn]);
        }
      }
    } else {
#pragma unroll
      for (int kk = 0; kk < 2; kk++) {
        const int u = kk * 4 + (lane >> 4);
        bf16x8 af[4];
#pragma unroll
        for (int fm = 0; fm < 4; fm++) af[fm] = LB(Abase, wm + fm * 16 + lr, u);
#pragma unroll
        for (int fn = 0; fn < 4; fn++) {
          bf16x8 bf = LB(Bbase, wn + fn * 16 + lr, u);
#pragma unroll
          for (int fm = 0; fm < 4; fm++) acc[fm][fn] = mfma16(af[fm], bf, acc[fm][fn]);
        }
      }
    }
  };

  // main loop: prefetch(k+1) via gll || compute(k); barrier drains both
  STAGE(smem, ck0);
  __syncthreads();
  int cur = 0;
  for (int kt = 0; kt < NK; ++kt) {
    if (kt + 1 < NK) STAGE(smem + (cur ^ 1) * BUFB, ck0 + kt + 1);
    COMPUTE(smem + cur * BUFB);
    __syncthreads();
    cur ^= 1;
  }

  // epilogue.  C/D layout: col = lane&15, row = (lane>>4)*4 + reg
  const int lr4 = (lane >> 4) * 4;
#pragma unroll
  for (int fm = 0; fm < 4; fm++) {
#pragma unroll
    for (int fn = 0; fn < 4; fn++) {
#pragma unroll
      for (int r = 0; r < 4; r++) {
        float v = acc[fm][fn][r];
        int row = wm + fm * 16 + lr4 + r;
        int col = wn + fn * 16 + lr;
        if constexpr (MODE == 0) {
          int gm = m0 + row, gn = n0 + col;
          v += bias[gn];
          int sec = gn >> 10, ee = gn & 1023, hh = ee >> 6, dd = ee & 63;
          if (sec == 0) v *= 0.125f;  // 1/sqrt(64), after bias like ref
          int ss = gm >> 1, bb = gm & 1, bhp = bb * 16 + hh;
          size_t base = ((size_t)bhp * 1024 + ss) * 64;
          bf16_t oh, ol; split2(v, oh, ol);
          if (sec == 0) {           // Q plain
            Qh[base + dd] = oh; Ql[base + dd] = ol;
          } else {                  // K/V swizzled (staged by gll in attn)
            size_t di = base + ((size_t)swslot(dd >> 3, ss) << 3) + (dd & 7);
            bf16_t* dh = (sec == 1) ? Kh2 : Vh2;
            bf16_t* dl = (sec == 1) ? Kl2 : Vl2;
            dh[di] = oh; dl[di] = ol;
          }
        } else if constexpr (MODE == 1) {
          int gm = m0 + row, gn = n0 + col;
          Cf[((size_t)kz * T_ + gm) * E_ + gn] = v;  // partial; bias/res in LN1
        } else if constexpr (MODE == 2) {
          int slot = m0 + row, gn = n0 + col;
          v += bias[e * DFF_ + gn];
          v = 0.5f * v * (1.0f + erff(v * 0.70710678118654752440f));  // exact gelu
          size_t byte = (size_t)slot * 8192 + (gn >> 6) * 128 +
                        (swslot((gn & 63) >> 3, slot) << 4) + (gn & 7) * 2;
          *(bf16_t*)((char*)Cb + byte) = (bf16_t)v;
        } else {
          int slot = m0 + row, gn = n0 + col;
          Cb[((size_t)kz * SLOTS_ + slot) * E_ + gn] = (bf16_t)v;  // bf16 partial
        }
      }
    }
  }
}

// ---------------------------------------------------------------------------
// V transpose: swizzled [bh][s][d] -> swizzled V^T [bh][d][s] (hi and lo).
// ---------------------------------------------------------------------------
__launch_bounds__(256)
__global__ void vtrans_kernel(const bf16_t* vh, const bf16_t* vl,
                              bf16_t* vth, bf16_t* vtl) {
  const int bh = blockIdx.y, s0 = blockIdx.x * 64;
  const int tid = threadIdx.x;
  __shared__ bf16_t th[64][72];
  __shared__ bf16_t tl[64][72];
#pragma unroll
  for (int i = 0; i < 2; i++) {
    int f = tid + i * 256, r = f >> 3, c = (f & 7) * 8;
    int s = s0 + r;
    size_t rowb = ((size_t)bh * 1024 + s) * 128;
    *(bf16x8*)&th[r][c] = *(const bf16x8*)((const char*)vh + rowb + (swslot(c >> 3, s) << 4));
    *(bf16x8*)&tl[r][c] = *(const bf16x8*)((const char*)vl + rowb + (swslot(c >> 3, s) << 4));
  }
  __syncthreads();
#pragma unroll
  for (int i = 0; i < 2; i++) {
    int f = tid + i * 256, d = f >> 3, c2 = (f & 7) * 8;
    bf16x8 oh, ol;
#pragma unroll
    for (int j = 0; j < 8; j++) { oh[j] = th[c2 + j][d]; ol[j] = tl[c2 + j][d]; }
    size_t ob = (((size_t)bh * 64 + d) * 1024 + s0) * 2;
    *(bf16x8*)((char*)vth + ob + (swslot(c2 >> 3, d) << 4)) = oh;
    *(bf16x8*)((char*)vtl + ob + (swslot(c2 >> 3, d) << 4)) = ol;
  }
}

// ---------------------------------------------------------------------------
// Flash attention, split-bf16, gll staging, XOR-swizzled LDS tiles.
// Block = (64 q-rows) x (one bh); 4 waves, 16 q-rows each; KV tiles of 64.
// ---------------------------------------------------------------------------
__launch_bounds__(256)
__global__ void attn_kernel(const bf16_t* gqh, const bf16_t* gql,
                            const bf16_t* gkh, const bf16_t* gkl,
                            const bf16_t* gvth, const bf16_t* gvtl,
                            bf16_t* ao) {
  const int bh = blockIdx.y, q0 = blockIdx.x * 64;
  const int tid = threadIdx.x, lane = tid & 63, wv = tid >> 6;
  const int lr = lane & 15, lk = (lane >> 4) * 8, lr4 = (lane >> 4) * 4;
  extern __shared__ char smem[];
  char* Kh = smem;
  char* Kl = smem + 8192;
  char* Vh = smem + 16384;   // V^T tile [d][64 t]
  char* Vl = smem + 24576;
  char* Ph = smem + 32768;   // P [64 q][64 t], per-wave private rows
  char* Pl = smem + 40960;

  const size_t qbase = ((size_t)bh * 1024 + q0 + wv * 16 + lr) * 64;  // Q plain
  bf16x8 qfh[2], qfl[2];
  qfh[0] = *(const bf16x8*)&gqh[qbase + lk];
  qfh[1] = *(const bf16x8*)&gqh[qbase + 32 + lk];
  qfl[0] = *(const bf16x8*)&gql[qbase + lk];
  qfl[1] = *(const bf16x8*)&gql[qbase + 32 + lk];

  f32x4 oacc[4];
#pragma unroll
  for (int i = 0; i < 4; i++) oacc[i] = (f32x4){0.f, 0.f, 0.f, 0.f};
  float m_r[4], l_r[4];
#pragma unroll
  for (int r = 0; r < 4; r++) { m_r[r] = -INFINITY; l_r[r] = 0.f; }

  for (int t0 = 0; t0 < S_; t0 += 64) {
    __syncthreads();  // previous tile fully consumed
#pragma unroll
    for (int i = 0; i < 2; i++) {
      int f = i * 256 + tid, row = f >> 3, cb = (f & 7) * 16;
      size_t koff = ((size_t)bh * 1024 + t0 + row) * 128 + cb;
      gll16((const char*)gkh + koff, Kh + f * 16);
      gll16((const char*)gkl + koff, Kl + f * 16);
      size_t voff = (((size_t)bh * 64 + row) * 1024 + t0) * 2 + cb;
      gll16((const char*)gvth + voff, Vh + f * 16);
      gll16((const char*)gvtl + voff, Vl + f * 16);
    }
    __syncthreads();  // staged data ready (vmcnt drained by barrier)

    f32x4 sacc[4];
#pragma unroll
    for (int i = 0; i < 4; i++) sacc[i] = (f32x4){0.f, 0.f, 0.f, 0.f};
#pragma unroll
    for (int kk = 0; kk < 2; ++kk) {
      const int u = kk * 4 + (lane >> 4);
#pragma unroll
      for (int fn = 0; fn < 4; ++fn) {
        int r = fn * 16 + lr;
        bf16x8 kbh = *(const bf16x8*)(Kh + r * 128 + (swslot(u, r) << 4));
        bf16x8 kbl = *(const bf16x8*)(Kl + r * 128 + (swslot(u, r) << 4));
        sacc[fn] = mfma16(qfh[kk], kbh, sacc[fn]);
        sacc[fn] = mfma16(qfh[kk], kbl, sacc[fn]);
        sacc[fn] = mfma16(qfl[kk], kbh, sacc[fn]);
      }
    }
    // online softmax; P rows are per-wave private -> no extra barrier needed
#pragma unroll
    for (int r = 0; r < 4; r++) {
      float mx = fmaxf(fmaxf(sacc[0][r], sacc[1][r]), fmaxf(sacc[2][r], sacc[3][r]));
#pragma unroll
      for (int off = 1; off < 16; off <<= 1) mx = fmaxf(mx, __shfl_xor(mx, off));
      float mn = fmaxf(m_r[r], mx);
      float al = __expf(m_r[r] - mn);
      l_r[r] *= al;
#pragma unroll
      for (int fd = 0; fd < 4; fd++) oacc[fd][r] *= al;
      float ps = 0.f;
      int pr = wv * 16 + lr4 + r;
#pragma unroll
      for (int fn = 0; fn < 4; fn++) {
        float p = __expf(sacc[fn][r] - mn);
        ps += p;
        bf16_t ph, pl; split2(p, ph, pl);
        int colu = (fn * 16 + lr) >> 3;
        int byte = pr * 128 + (swslot(colu, pr) << 4) + ((lr & 7) * 2);
        *(bf16_t*)(Ph + byte) = ph;
        *(bf16_t*)(Pl + byte) = pl;
      }
#pragma unroll
      for (int off = 1; off < 16; off <<= 1) ps += __shfl_xor(ps, off);
      l_r[r] += ps;
      m_r[r] = mn;
    }
    // PV
#pragma unroll
    for (int kk = 0; kk < 2; kk++) {
      const int u = kk * 4 + (lane >> 4);
      int pr2 = wv * 16 + lr;
      bf16x8 pah = *(const bf16x8*)(Ph + pr2 * 128 + (swslot(u, pr2) << 4));
      bf16x8 pal = *(const bf16x8*)(Pl + pr2 * 128 + (swslot(u, pr2) << 4));
#pragma unroll
      for (int fd = 0; fd < 4; fd++) {
        int rd = fd * 16 + lr;
        bf16x8 vbh = *(const bf16x8*)(Vh + rd * 128 + (swslot(u, rd) << 4));
        bf16x8 vbl = *(const bf16x8*)(Vl + rd * 128 + (swslot(u, rd) << 4));
        oacc[fd] = mfma16(pah, vbh, oacc[fd]);
        oacc[fd] = mfma16(pah, vbl, oacc[fd]);
        oacc[fd] = mfma16(pal, vbh, oacc[fd]);
      }
    }
  }
  // epilogue -> ao: split-interleaved pre-swizzled rows (OUTPROJ A format)
  const int b = bh >> 4, h = bh & 15;
#pragma unroll
  for (int fd = 0; fd < 4; fd++) {
#pragma unroll
    for (int r = 0; r < 4; r++) {
      float v = oacc[fd][r] / l_r[r];
      int s = q0 + wv * 16 + lr4 + r;
      int d = fd * 16 + lr;
      int tok = s * 2 + b;
      int chunk = h * 2 + (d >> 5);
      int w = d & 31;
      bf16_t oh, ol; split2(v, oh, ol);
      size_t rb = (size_t)tok * 4096 + chunk * 128;
      *(bf16_t*)((char*)ao + rb + (swslot(w >> 3, tok) << 4) + (w & 7) * 2) = oh;
      *(bf16_t*)((char*)ao + rb + (swslot(4 + (w >> 3), tok) << 4) + (w & 7) * 2) = ol;
    }
  }
}

// ---------------------------------------------------------------------------
// LN1 fused with out_proj split-K reduce + bias + x residual -> l1f (f32)
// ---------------------------------------------------------------------------
__launch_bounds__(256)
__global__ void ln1_kernel(const float* p0, const float* p1, const float* x,
                           const float* opb, const float* g, const float* bt,
                           float* l1f) {
  const int row = blockIdx.x, tid = threadIdx.x;
  const int j = tid * 4;
  f32x4 v = *(const f32x4*)&p0[(size_t)row * 1024 + j];
  f32x4 v1 = *(const f32x4*)&p1[(size_t)row * 1024 + j];
  f32x4 xr = *(const f32x4*)&x[(size_t)row * 1024 + j];
  f32x4 bb2 = *(const f32x4*)&opb[j];
#pragma unroll
  for (int i = 0; i < 4; i++) v[i] += v1[i] + xr[i] + bb2[i];
  float s = v[0] + v[1] + v[2] + v[3];
  float q = v[0] * v[0] + v[1] * v[1] + v[2] * v[2] + v[3] * v[3];
#pragma unroll
  for (int off = 1; off < 64; off <<= 1) { s += __shfl_xor(s, off); q += __shfl_xor(q, off); }
  __shared__ float ss[4], qq[4];
  int wv = tid >> 6;
  if ((tid & 63) == 0) { ss[wv] = s; qq[wv] = q; }
  __syncthreads();
  s = ss[0] + ss[1] + ss[2] + ss[3];
  q = qq[0] + qq[1] + qq[2] + qq[3];
  float mu = s * (1.f / 1024.f);
  float var = q * (1.f / 1024.f) - mu * mu;
  float rs = rsqrtf(var + 1e-5f);
  f32x4 gg = *(const f32x4*)&g[j];
  f32x4 bb = *(const f32x4*)&bt[j];
  f32x4 o;
#pragma unroll
  for (int jj = 0; jj < 4; jj++) o[jj] = (v[jj] - mu) * rs * gg[jj] + bb[jj];
  *(f32x4*)&l1f[(size_t)row * 1024 + j] = o;
}

// ---------------------------------------------------------------------------
// LN2 fused with MoE split-K reduce (bf16 partials) + b2 + l1f residual.
// ---------------------------------------------------------------------------
__launch_bounds__(256)
__global__ void ln2_kernel(const bf16_t* part, const float* l1f, const float* b2,
                           const int* eid, const int* inv, const float* g,
                           const float* bt, float* out) {
  const int t = blockIdx.x, tid = threadIdx.x;
  const int st = inv[t], e = eid[t];
  const int j = tid * 4;
  f32x4 v = (f32x4){0.f, 0.f, 0.f, 0.f};
#pragma unroll
  for (int kz = 0; kz < SPLITK_; kz++) {
    bf16x4 p = *(const bf16x4*)&part[((size_t)kz * SLOTS_ + st) * 1024 + j];
#pragma unroll
    for (int i = 0; i < 4; i++) v[i] += (float)p[i];
  }
  f32x4 bb2 = *(const f32x4*)&b2[e * 1024 + j];
  f32x4 rr = *(const f32x4*)&l1f[(size_t)t * 1024 + j];
#pragma unroll
  for (int i = 0; i < 4; i++) v[i] += bb2[i] + rr[i];
  float s = v[0] + v[1] + v[2] + v[3];
  float q = v[0] * v[0] + v[1] * v[1] + v[2] * v[2] + v[3] * v[3];
#pragma unroll
  for (int off = 1; off < 64; off <<= 1) { s += __shfl_xor(s, off); q += __shfl_xor(q, off); }
  __shared__ float ss[4], qq[4];
  int wv = tid >> 6;
  if ((tid & 63) == 0) { ss[wv] = s; qq[wv] = q; }
  __syncthreads();
  s = ss[0] + ss[1] + ss[2] + ss[3];
  q = qq[0] + qq[1] + qq[2] + qq[3];
  float mu = s * (1.f / 1024.f);
  float var = q * (1.f / 1024.f) - mu * mu;
  float rs = rsqrtf(var + 1e-5f);
  f32x4 gg = *(const f32x4*)&g[j];
  f32x4 bb = *(const f32x4*)&bt[j];
  f32x4 o;
#pragma unroll
  for (int jj = 0; jj < 4; jj++) o[jj] = (v[jj] - mu) * rs * gg[jj] + bb[jj];
  *(f32x4*)&out[(size_t)t * 1024 + j] = o;
}

// ---------------------------------------------------------------------------
// Gate: fp32 logits, first-max argmax, per-expert counts.
// ---------------------------------------------------------------------------
__launch_bounds__(256)
__global__ void gate_kernel(const float* ln1f, const float* gw, const float* gb,
                            int* eid, int* cnt) {
  const int t = blockIdx.x * 4 + (threadIdx.x >> 6);
  const int lane = threadIdx.x & 63;
  float a[8] = {0, 0, 0, 0, 0, 0, 0, 0};
  for (int k0 = lane * 4; k0 < 1024; k0 += 256) {
    f32x4 xv = *(const f32x4*)&ln1f[(size_t)t * 1024 + k0];
#pragma unroll
    for (int ee = 0; ee < 8; ee++) {
      f32x4 wv4 = *(const f32x4*)&gw[ee * 1024 + k0];
      a[ee] += xv[0] * wv4[0] + xv[1] * wv4[1] + xv[2] * wv4[2] + xv[3] * wv4[3];
    }
  }
#pragma unroll
  for (int ee = 0; ee < 8; ee++)
#pragma unroll
    for (int off = 1; off < 64; off <<= 1) a[ee] += __shfl_xor(a[ee], off);
  if (lane == 0) {
    float best = a[0] + gb[0];
    int be = 0;
#pragma unroll
    for (int ee = 1; ee < 8; ee++) {
      float vv = a[ee] + gb[ee];
      if (vv > best) { best = vv; be = ee; }
    }
    eid[t] = be;
    atomicAdd(&cnt[be], 1);
  }
}

__global__ void zero_kernel(int* cnt) {
  if (threadIdx.x < 8) cnt[threadIdx.x] = 0;
}

__global__ void scan_kernel(const int* cnt, int* offs_pad, int* cur) {
  if (threadIdx.x == 0) {
    int op = 0;
    for (int e = 0; e < 8; e++) {
      offs_pad[e] = op;
      op += (cnt[e] + 127) & ~127;
      cur[e] = 0;
    }
    offs_pad[8] = op;
  }
}

__global__ void scatter_kernel(const int* eid, const int* offs_pad, int* cur,
                               int* perm, int* inv) {
  int t = blockIdx.x * 256 + threadIdx.x;
  int ee = eid[t];
  int pos = atomicAdd(&cur[ee], 1);
  int slot = offs_pad[ee] + pos;
  perm[slot] = t;
  inv[t] = slot;
}

// ---------------------------------------------------------------------------
extern "C" void kernel_launch(void* const* d_in, const int* in_sizes, int n_in,
                              void* d_out, int out_size, void* d_ws, size_t ws_size,
                              hipStream_t stream) {
  const float* x    = (const float*)d_in[0];
  const float* ipw  = (const float*)d_in[1];
  const float* ipb  = (const float*)d_in[2];
  const float* opw  = (const float*)d_in[3];
  const float* opb  = (const float*)d_in[4];
  const float* ln1g = (const float*)d_in[5];
  const float* ln1b = (const float*)d_in[6];
  const float* ln2g = (const float*)d_in[7];
  const float* ln2b = (const float*)d_in[8];
  const float* gw   = (const float*)d_in[9];
  const float* gb   = (const float*)d_in[10];
  const float* w1   = (const float*)d_in[11];
  const float* b1   = (const float*)d_in[12];
  const float* w2   = (const float*)d_in[13];
  const float* b2   = (const float*)d_in[14];
  float* out = (float*)d_out;

  char* w = (char*)d_ws;
  auto alloc = [&](size_t n) { char* p = w; w += (n + 255) & ~(size_t)255; return p; };
  const size_t MB = 1u << 20;

  // Region 1: w1prep [start->MOE1]  ∪  partb [MOE2->LN2]
  char* R1 = alloc(64 * MB);
  bf16_t* w1p   = (bf16_t*)R1;
  bf16_t* partb = (bf16_t*)R1;
  // Region 2: w2prep [start->MOE2]
  bf16_t* w2p = (bf16_t*)alloc(64 * MB);
  // Region 3: xprep [start->QKV] ∪ l1g [LN1->MOE1]
  char* R3 = alloc(8 * MB);
  bf16_t* xp  = (bf16_t*)R3;
  bf16_t* l1g = (bf16_t*)R3;
  // Region 4/5: ipw/opw preps [start->QKV/OUTPROJ]
  bf16_t* ipwp = (bf16_t*)alloc(12 * MB);
  bf16_t* opwp = (bf16_t*)alloc(4 * MB);
  // Region 6: QKV buffers [QKV->attn] ∪ hbuf [MOE1->MOE2]
  char* R6 = alloc(32 * MB);
  bf16_t* qh  = (bf16_t*)(R6 + 0 * MB);
  bf16_t* ql  = (bf16_t*)(R6 + 4 * MB);
  bf16_t* kh  = (bf16_t*)(R6 + 8 * MB);
  bf16_t* kl  = (bf16_t*)(R6 + 12 * MB);
  bf16_t* vh  = (bf16_t*)(R6 + 16 * MB);
  bf16_t* vl  = (bf16_t*)(R6 + 20 * MB);
  bf16_t* vth = (bf16_t*)(R6 + 24 * MB);
  bf16_t* vtl = (bf16_t*)(R6 + 28 * MB);
  bf16_t* hbuf = (bf16_t*)R6;
  // Region 7-9
  bf16_t* ao    = (bf16_t*)alloc(8 * MB);
  float*  pre1p = (float*)alloc(16 * MB);   // 2 split-K partials
  float*  l1f   = (float*)alloc(8 * MB);
  int* eid   = (int*)alloc(T_ * 4);
  int* cnt   = (int*)alloc(16 * 4);
  int* offsp = (int*)alloc(16 * 4);
  int* cur   = (int*)alloc(16 * 4);
  int* perm  = (int*)alloc(SLOTS_ * 4);
  int* inv   = (int*)alloc(T_ * 4);

  const dim3 blk(256);
  const int smemGemm = 65536;
  const int smemAttn = 49152;

  zero_kernel<<<1, 64, 0, stream>>>(cnt);
  hipMemsetAsync(perm, 0, SLOTS_ * 4, stream);

  // 0) weight/activation prep (bf16, pre-swizzled)
  prep_wsplit<<<dim3(1536), blk, 0, stream>>>(ipw, ipwp);   // 3072 rows
  prep_wsplit<<<dim3(512),  blk, 0, stream>>>(opw, opwp);   // 1024 rows
  prep_wsplit<<<dim3(1024), blk, 0, stream>>>(x, xp);       // 2048 rows
  prep_w<16, 4><<<dim3(16384), blk, 0, stream>>>(w1, w1p);  // 32768 rows, K=1024
  prep_w<64, 6><<<dim3(16384), blk, 0, stream>>>(w2, w2p);  // 8192 rows,  K=4096

  // 1) QKV projection (split) -> Q plain / K,V swizzled, hi/lo
  gemm_kernel<0><<<dim3(24, 16, 1), blk, smemGemm, stream>>>(
      xp, ipwp, ipb, nullptr, nullptr, qh, ql, kh, kl, vh, vl, nullptr);

  // 2) V transpose -> swizzled V^T
  vtrans_kernel<<<dim3(16, 32), blk, 0, stream>>>(vh, vl, vth, vtl);

  // 3) flash attention -> ao (split-interleaved, pre-swizzled)
  attn_kernel<<<dim3(16, 32), blk, smemAttn, stream>>>(qh, ql, kh, kl, vth, vtl, ao);

  // 4) out_proj split-K=2 -> fp32 partials
  gemm_kernel<1><<<dim3(8, 16, 2), blk, smemGemm, stream>>>(
      ao, opwp, nullptr, pre1p, nullptr,
      nullptr, nullptr, nullptr, nullptr, nullptr, nullptr, nullptr);

  // 5) LN1 (fused reduce + opb + x residual) -> l1f
  ln1_kernel<<<dim3(T_), blk, 0, stream>>>(pre1p, pre1p + (size_t)T_ * E_, x, opb,
                                           ln1g, ln1b, l1f);

  // 6) gate + routing + slot-major gather (pre-swizzled MOE1 A)
  gate_kernel<<<dim3(T_ / 4), blk, 0, stream>>>(l1f, gw, gb, eid, cnt);
  scan_kernel<<<1, 64, 0, stream>>>(cnt, offsp, cur);
  scatter_kernel<<<dim3(T_ / 256), blk, 0, stream>>>(eid, offsp, cur, perm, inv);
  gather_kernel<<<dim3(1536), blk, 0, stream>>>(l1f, perm, l1g);

  // 7) expert FFN up -> hbuf (bf16, swizzled)
  gemm_kernel<2><<<dim3(32, 24, 1), blk, smemGemm, stream>>>(
      l1g, w1p, b1, nullptr, hbuf,
      nullptr, nullptr, nullptr, nullptr, nullptr, nullptr, offsp);

  // 8) expert FFN down split-K=4 -> bf16 partials
  gemm_kernel<3><<<dim3(8, 24, SPLITK_), blk, smemGemm, stream>>>(
      hbuf, w2p, nullptr, nullptr, partb,
      nullptr, nullptr, nullptr, nullptr, nullptr, nullptr, offsp);

  // 9) LN2 (fused reduce + b2 + residual) -> out
  ln2_kernel<<<dim3(T_), blk, 0, stream>>>(partb, l1f, b2, eid, inv, ln2g, ln2b, out);

  (void)in_sizes; (void)n_in; (void)out_size; (void)ws_size;
}